// Round 3
// baseline (488.333 us; speedup 1.0000x reference)
//
#include <hip/hip_runtime.h>
#include <stdint.h>
#include <math.h>

#define NB 8
#define NQ 512

// ws layout (bytes):
//   [0      ) cost bits : NB*NQ*8 u64 = 262144  (bit l of word k of row i = cost[i][64k+l])
//   [262144 ) cols      : NB*NQ  i32  = 16384

// Fused prep+cost: computes xyxy conversions inline (bit-identical to the
// reference: Kalman innovation == 0 exactly, so filtered = (prev*scale)/scale).
__global__ void cost_kernel(const float* __restrict__ prev_boxes,
                            const float* __restrict__ curr_boxes,
                            const float* __restrict__ image_sizes,
                            unsigned long long* __restrict__ cost,
                            float* __restrict__ out) {
#pragma clang fp contract(off)
    int t = blockIdx.x * blockDim.x + threadIdx.x;   // 0 .. NB*NQ*NQ-1
    if (t == 0) out[0] = 0.f;
    int b = t >> 18;
    int rem = t & (NQ * NQ - 1);
    int i = rem >> 9;        // row: curr box
    int j = rem & (NQ - 1);  // col: filtered box
    float4 cb = ((const float4*)curr_boxes)[(b << 9) + i];
    float ax = cb.x - 0.5f * cb.z, ay = cb.y - 0.5f * cb.w;
    float az = cb.x + 0.5f * cb.z, aw = cb.y + 0.5f * cb.w;
    float H = image_sizes[2 * b + 0];
    float W = image_sizes[2 * b + 1];
    float4 pb = ((const float4*)prev_boxes)[(b << 9) + j];
    float fcx = (pb.x * W) / W, fcy = (pb.y * H) / H;
    float fw  = (pb.z * W) / W, fh  = (pb.w * H) / H;
    float bx = fcx - 0.5f * fw, by = fcy - 0.5f * fh;
    float bz = fcx + 0.5f * fw, bw = fcy + 0.5f * fh;
    float area_a = (az - ax) * (aw - ay);
    float area_b = (bz - bx) * (bw - by);
    float ltx = fmaxf(ax, bx), lty = fmaxf(ay, by);
    float rbx = fminf(az, bz), rby = fminf(aw, bw);
    float w = fmaxf(rbx - ltx, 0.f), h = fmaxf(rby - lty, 0.f);
    float inter = w * h;
    float uni = area_a + area_b - inter;
    float iou = inter / (uni + 1e-7f);
    float lcx = fminf(ax, bx), lcy = fminf(ay, by);
    float rcx = fmaxf(az, bz), rcy = fmaxf(aw, bw);
    float wc = fmaxf(rcx - lcx, 0.f), hc = fmaxf(rcy - lcy, 0.f);
    float areac = wc * hc;
    float giou = iou - (areac - uni) / (areac + 1e-7f);
    float gl = 1.f - giou;
    unsigned long long m = __ballot(gl < 0.2f);
    if ((threadIdx.x & 63) == 0)
        cost[((size_t)((b << 9) + i)) * 8 + (j >> 6)] = m;
}

// Exact integer replication of the reference JV Hungarian on a {0,1} cost
// matrix. Cost matrix staged in LDS; lane-0 serial loop with 512-bit bitset
// state in registers; owner row Z == costL[p[c]-1] (no separate table).
// Latency pipeline: next row's Z issued at row top; p[c1_next] prefetched
// right after this row's augment writes (same-wave LDS ops are ordered);
// owner-row read issued as soon as pc lands. Fold records (<=3) keep the
// way-chain in registers; folds >=4 spill tagged way bits to LDS (rare).
// Any delta>0 event bails to the exact general integer JV (sticky).
__global__ __launch_bounds__(64, 1) void hungarian_kernel(
        const unsigned long long* __restrict__ cost, int* __restrict__ cols) {
    int b = blockIdx.x;
    int lane = threadIdx.x;
    __shared__ __align__(16) unsigned long long costL[NQ * 8];   // 32 KB
    __shared__ int p[NQ + 1];
    __shared__ int wayL[NQ + 1];
    __shared__ int u[NQ + 1];
    __shared__ int vv[NQ + 1];
    __shared__ int minvA[NQ + 1];
    __shared__ unsigned char used[NQ + 1];
    __shared__ unsigned long long rows_nz[8];

    {
        const ulonglong2* src = (const ulonglong2*)(cost + (size_t)b * NQ * 8);
        ulonglong2* dst = (ulonglong2*)costL;
        for (int k = lane; k < NQ * 4; k += 64) dst[k] = src[k];
    }
    for (int k = lane; k <= NQ; k += 64) { p[k] = 0; wayL[k] = 0; u[k] = 0; vv[k] = 0; }
    __syncthreads();
    for (int w = 0; w < 8; w++) {
        const unsigned long long* rw = costL + (((w << 6) + lane) << 3);
        unsigned long long o = 0ull;
#pragma unroll
        for (int k = 0; k < 8; k++) o |= rw[k];
        unsigned long long bal = __ballot(o != 0ull);
        if (lane == 0) rows_nz[w] = bal;
    }
    __syncthreads();

    if (lane == 0) {
        unsigned long long freeb[8];
#pragma unroll
        for (int k = 0; k < 8; k++) freeb[k] = ~0ull;
        bool general = false;

        unsigned long long Znext[8];
        int c1next, pc_pre;
        {
#pragma unroll
            for (int k = 0; k < 8; k++) Znext[k] = costL[k];
            int cn = -1;
#pragma unroll
            for (int k = 0; k < 8; k++) {
                unsigned long long s = ~Znext[k];
                if (cn < 0 && s != 0ull) cn = (k << 6) + __builtin_ctzll(s);
            }
            c1next = cn;
            pc_pre = p[(cn < 0 ? 0 : cn) + 1];
        }

        for (int i = 1; i <= NQ; i++) {
            bool rowGeneral = general;
            if (!rowGeneral) {
                unsigned long long Zcur[8];
#pragma unroll
                for (int k = 0; k < 8; k++) Zcur[k] = Znext[k];
                int c1 = c1next;
                int pc0 = pc_pre;
                // issue next-row Z load early (independent of this row's writes)
                if (i < NQ) {
#pragma unroll
                    for (int k = 0; k < 8; k++) Znext[k] = costL[(i << 3) + k];
                }
                // issue owner-row read for the first visit asap
                unsigned long long Zo[8];
                if (pc0 > 0) {
#pragma unroll
                    for (int k = 0; k < 8; k++) Zo[k] = costL[((pc0 - 1) << 3) + k];
                }
                bool nzrow = (rows_nz[(i - 1) >> 6] >> ((i - 1) & 63)) & 1ull;
                bool bail = false;
                if (!nzrow) {
                    // all-zero row: assigns lowest free column (no-op walk)
                    int jf = -1;
#pragma unroll
                    for (int k = 0; k < 8; k++)
                        if (jf < 0 && freeb[k] != 0ull) jf = (k << 6) + __builtin_ctzll(freeb[k]);
                    freeb[jf >> 6] &= ~(1ull << (jf & 63));
                    p[jf + 1] = i;
                } else {
                    unsigned long long ones[8], vis[8];
#pragma unroll
                    for (int k = 0; k < 8; k++) { ones[k] = Zcur[k]; vis[k] = 0ull; }
                    int foldn = 0;
                    int fj0[3], fpo[3];
                    unsigned long long fnz[3][8];
                    int assignTo = -1;
                    int c = c1, pc = pc0;
                    bool first = true;
                    while (true) {
                        if (c < 0) { bail = true; break; }  // delta>0 needed
                        if (!first) {
                            pc = p[c + 1];
                            if (pc > 0) {
#pragma unroll
                                for (int k = 0; k < 8; k++) Zo[k] = costL[((pc - 1) << 3) + k];
                            }
                        }
                        first = false;
                        if (pc == 0) { assignTo = c; break; }
                        // visit c: fold owner's row into minv
                        vis[c >> 6] |= 1ull << (c & 63);
                        unsigned long long ap = 0ull, nz[8];
#pragma unroll
                        for (int k = 0; k < 8; k++) {
                            nz[k] = ones[k] & ~Zo[k];
                            ones[k] &= Zo[k];
                            ap |= ones[k];
                        }
                        if (foldn < 3) {
                            fj0[foldn] = c; fpo[foldn] = pc;
#pragma unroll
                            for (int k = 0; k < 8; k++) fnz[foldn][k] = nz[k];
                        } else {
#pragma unroll
                            for (int k = 0; k < 8; k++) {
                                unsigned long long tt = nz[k];
                                while (tt) {
                                    int bb2 = __builtin_ctzll(tt); tt &= tt - 1;
                                    wayL[(k << 6) + bb2 + 1] = (i << 10) | (c + 1);
                                }
                            }
                        }
                        foldn++;
                        if (ap == 0ull) {
                            // shortcut: rest of walk is a provable no-op
                            int jf = -1;
#pragma unroll
                            for (int k = 0; k < 8; k++)
                                if (jf < 0 && freeb[k] != 0ull) jf = (k << 6) + __builtin_ctzll(freeb[k]);
                            assignTo = jf;
                            break;
                        }
                        int cn2 = -1;
#pragma unroll
                        for (int k = 0; k < 8; k++) {
                            unsigned long long s = ~ones[k] & ~vis[k];
                            if (cn2 < 0 && s != 0ull) cn2 = (k << 6) + __builtin_ctzll(s);
                        }
                        c = cn2;
                    }
                    if (!bail) {
                        // augment (each column in at most one fold's nz set)
                        freeb[assignTo >> 6] &= ~(1ull << (assignTo & 63));
                        int cc = assignTo;
                        while (true) {
                            int pf = -1;
#pragma unroll
                            for (int f = 0; f < 3; f++)
                                if (f < foldn && ((fnz[f][cc >> 6] >> (cc & 63)) & 1ull)) pf = f;
                            if (pf >= 0) {
                                p[cc + 1] = fpo[pf];
                                cc = fj0[pf];
                            } else {
                                int pcn2 = 0;
                                if (foldn > 3) {
                                    int wv = wayL[cc + 1];
                                    pcn2 = ((wv >> 10) == i) ? (wv & 1023) : 0;
                                }
                                if (pcn2 == 0) { p[cc + 1] = i; break; }
                                p[cc + 1] = p[pcn2];
                                cc = pcn2 - 1;
                            }
                        }
                    }
                }
                if (bail) { general = true; rowGeneral = true; }
                else if (i < NQ) {
                    // prefetch p[c1] for next row (after this row's writes;
                    // same-wave LDS ops are ordered)
                    int cn = -1;
#pragma unroll
                    for (int k = 0; k < 8; k++) {
                        unsigned long long s = ~Znext[k];
                        if (cn < 0 && s != 0ull) cn = (k << 6) + __builtin_ctzll(s);
                    }
                    c1next = cn;
                    pc_pre = p[(cn < 0 ? 0 : cn) + 1];
                }
            }
            if (rowGeneral) {
                // fully general integer JV (exact reference semantics);
                // iter-1 rewrites way for every unused column, so stale
                // fast-path tags cannot leak.
                p[0] = i;
                for (int j = 0; j <= NQ; j++) { minvA[j] = 0x7fffffff; used[j] = 0; }
                int j0 = 0;
                while (true) {
                    used[j0] = 1;
                    int i0 = p[j0];
                    int ui0 = u[i0];
                    const unsigned long long* rr = costL + ((size_t)(i0 - 1) << 3);
                    int delta = 0x7fffffff, j1 = 0;
                    for (int j = 1; j <= NQ; j++) {
                        if (!used[j]) {
                            int cbit = (int)((rr[(j - 1) >> 6] >> ((j - 1) & 63)) & 1ull);
                            int cur = cbit - ui0 - vv[j];
                            if (cur < minvA[j]) { minvA[j] = cur; wayL[j] = (i << 10) | j0; }
                            if (minvA[j] < delta) { delta = minvA[j]; j1 = j; }
                        }
                    }
                    for (int j = 0; j <= NQ; j++) {
                        if (used[j]) { u[p[j]] += delta; vv[j] -= delta; }
                        else minvA[j] -= delta;
                    }
                    j0 = j1;
                    if (p[j0] == 0) break;
                }
                while (j0) {
                    int wv = wayL[j0];
                    int jn = ((wv >> 10) == i) ? (wv & 1023) : 0;
                    p[j0] = p[jn];
                    j0 = jn;
                }
            }
        }
    }
    __syncthreads();
#pragma unroll
    for (int k = 0; k < 8; k++) {
        int j = 1 + lane + (k << 6);
        cols[b * NQ + (p[j] - 1)] = j - 1;
    }
}

// Fused gather+xyxy+CIoU+mean (conversions recomputed inline, bit-identical).
__global__ void ciou_kernel(const float* __restrict__ prev_boxes,
                            const float* __restrict__ curr_boxes,
                            const float* __restrict__ image_sizes,
                            const int* __restrict__ cols,
                            float* __restrict__ out) {
#pragma clang fp contract(off)
    int idx = blockIdx.x * blockDim.x + threadIdx.x;
    float term = 0.f;
    if (idx < NB * NQ) {
        int b = idx >> 9;
        int c = cols[idx];
        float4 cb = ((const float4*)curr_boxes)[(b << 9) + c];
        float x1 = cb.x - 0.5f * cb.z, y1 = cb.y - 0.5f * cb.w;
        float x2 = cb.x + 0.5f * cb.z, y2 = cb.y + 0.5f * cb.w;
        float H = image_sizes[2 * b + 0];
        float W = image_sizes[2 * b + 1];
        float4 pb = ((const float4*)prev_boxes)[idx];
        float fcx = (pb.x * W) / W, fcy = (pb.y * H) / H;
        float fw  = (pb.z * W) / W, fh  = (pb.w * H) / H;
        float xg1 = fcx - 0.5f * fw, yg1 = fcy - 0.5f * fh;
        float xg2 = fcx + 0.5f * fw, yg2 = fcy + 0.5f * fh;
        float iw = fmaxf(fminf(x2, xg2) - fmaxf(x1, xg1), 0.f);
        float ih = fmaxf(fminf(y2, yg2) - fmaxf(y1, yg1), 0.f);
        float inter = iw * ih;
        float uni = (x2 - x1) * (y2 - y1) + (xg2 - xg1) * (yg2 - yg1) - inter;
        float iou = inter / (uni + 1e-7f);
        float cw = fmaxf(x2, xg2) - fminf(x1, xg1);
        float ch = fmaxf(y2, yg2) - fminf(y1, yg1);
        float c2 = cw * cw + ch * ch + 1e-7f;
        float dx = ((x1 + x2) - xg1) - xg2;
        float dy = ((y1 + y2) - yg1) - yg2;
        float d2 = (dx * dx + dy * dy) / 4.f;
        const float C = (float)(4.0 / (M_PI * M_PI));
        float at = atanf((xg2 - xg1) / (yg2 - yg1)) - atanf((x2 - x1) / (y2 - y1));
        float v = C * (at * at);
        float alpha = v / (((1.f - iou) + v) + 1e-7f);
        term = ((1.f - iou) + d2 / c2) + alpha * v;
    }
#pragma unroll
    for (int off = 32; off >= 1; off >>= 1) term += __shfl_xor(term, off, 64);
    if ((threadIdx.x & 63) == 0) atomicAdd(out, term * (1.f / 4096.f));
}

extern "C" void kernel_launch(void* const* d_in, const int* in_sizes, int n_in,
                              void* d_out, int out_size, void* d_ws, size_t ws_size,
                              hipStream_t stream) {
    const float* prev_boxes  = (const float*)d_in[0];
    // d_in[1] = prev_logits : dead code (Kalman innovation == 0 exactly)
    const float* curr_boxes  = (const float*)d_in[2];
    const float* image_sizes = (const float*)d_in[3];
    // d_in[4..6] (std weights, log_q_diag) : dead code

    char* ws = (char*)d_ws;
    unsigned long long* cost = (unsigned long long*)(ws);
    int* cols  = (int*)(ws + 262144);
    float* out = (float*)d_out;

    cost_kernel<<<(NB * NQ * NQ) / 256, 256, 0, stream>>>(
        prev_boxes, curr_boxes, image_sizes, cost, out);
    hungarian_kernel<<<NB, 64, 0, stream>>>(cost, cols);
    ciou_kernel<<<16, 256, 0, stream>>>(prev_boxes, curr_boxes, image_sizes, cols, out);
}

// Round 5
// 322.223 us; speedup vs baseline: 1.5155x; 1.5155x over previous
//
#include <hip/hip_runtime.h>
#include <stdint.h>
#include <math.h>

#define NB 8
#define NQ 512

// ws layout (bytes):
//   [0) cost bits : NB*NQ*8 u64 = 262144  (bit l of word k of row i = cost[i][64k+l])

// Fused prep+cost: xyxy conversions inline (bit-identical to reference:
// Kalman innovation == 0 exactly, so filtered = (prev*scale)/scale).
__global__ void cost_kernel(const float* __restrict__ prev_boxes,
                            const float* __restrict__ curr_boxes,
                            const float* __restrict__ image_sizes,
                            unsigned long long* __restrict__ cost,
                            float* __restrict__ out) {
#pragma clang fp contract(off)
    int t = blockIdx.x * blockDim.x + threadIdx.x;   // 0 .. NB*NQ*NQ-1
    if (t == 0) out[0] = 0.f;
    int b = t >> 18;
    int rem = t & (NQ * NQ - 1);
    int i = rem >> 9;        // row: curr box
    int j = rem & (NQ - 1);  // col: filtered box
    float4 cb = ((const float4*)curr_boxes)[(b << 9) + i];
    float ax = cb.x - 0.5f * cb.z, ay = cb.y - 0.5f * cb.w;
    float az = cb.x + 0.5f * cb.z, aw = cb.y + 0.5f * cb.w;
    float H = image_sizes[2 * b + 0];
    float W = image_sizes[2 * b + 1];
    float4 pb = ((const float4*)prev_boxes)[(b << 9) + j];
    float fcx = (pb.x * W) / W, fcy = (pb.y * H) / H;
    float fw  = (pb.z * W) / W, fh  = (pb.w * H) / H;
    float bx = fcx - 0.5f * fw, by = fcy - 0.5f * fh;
    float bz = fcx + 0.5f * fw, bw = fcy + 0.5f * fh;
    float area_a = (az - ax) * (aw - ay);
    float area_b = (bz - bx) * (bw - by);
    float ltx = fmaxf(ax, bx), lty = fmaxf(ay, by);
    float rbx = fminf(az, bz), rby = fminf(aw, bw);
    float w = fmaxf(rbx - ltx, 0.f), h = fmaxf(rby - lty, 0.f);
    float inter = w * h;
    float uni = area_a + area_b - inter;
    float iou = inter / (uni + 1e-7f);
    float lcx = fminf(ax, bx), lcy = fminf(ay, by);
    float rcx = fmaxf(az, bz), rcy = fmaxf(aw, bw);
    float wc = fmaxf(rcx - lcx, 0.f), hc = fmaxf(rcy - lcy, 0.f);
    float areac = wc * hc;
    float giou = iou - (areac - uni) / (areac + 1e-7f);
    float gl = 1.f - giou;
    unsigned long long m = __ballot(gl < 0.2f);
    if ((threadIdx.x & 63) == 0)
        cost[((size_t)((b << 9) + i)) * 8 + (j >> 6)] = m;
}

// Exact integer replication of the reference JV Hungarian on a {0,1} cost
// matrix + fused CIoU epilogue. Cost matrix staged in LDS; lane-0 serial
// loop with 512-bit bitset state in registers.
// Register discipline (the R3 lesson): NO dynamic indexing into register
// arrays — every bit test/set uses the unrolled (k==wd) select trick.
// Occupancy of a column comes from the freeb register bitset, so zero rows
// and free-first-candidate rows touch no LDS on the critical path. Occupied
// visits read p[c] + owner row from LDS. Folds <=2 recorded in registers
// (nzA/nzB); folds >=3 spill tagged way bits to LDS (rare). Any delta>0
// event bails to the exact general integer JV (sticky); the bailed attempt
// leaves only way-tags, which general's iter-1 fully rewrites.
__global__ __launch_bounds__(64, 1) void hungarian_kernel(
        const unsigned long long* __restrict__ cost,
        const float* __restrict__ prev_boxes,
        const float* __restrict__ curr_boxes,
        const float* __restrict__ image_sizes,
        float* __restrict__ out) {
    int b = blockIdx.x;
    int lane = threadIdx.x;
    __shared__ __align__(16) unsigned long long costL[NQ * 8];   // 32 KB
    __shared__ int p[NQ + 1];
    __shared__ int wayL[NQ + 1];
    __shared__ int u[NQ + 1];
    __shared__ int vv[NQ + 1];
    __shared__ int minvA[NQ + 1];
    __shared__ unsigned char used[NQ + 1];
    __shared__ unsigned long long rows_nz[8];

    {
        const ulonglong2* src = (const ulonglong2*)(cost + (size_t)b * NQ * 8);
        ulonglong2* dst = (ulonglong2*)costL;
        for (int k = lane; k < NQ * 4; k += 64) dst[k] = src[k];
    }
    for (int k = lane; k <= NQ; k += 64) { p[k] = 0; wayL[k] = 0; u[k] = 0; vv[k] = 0; }
    __syncthreads();
    for (int w = 0; w < 8; w++) {
        const unsigned long long* rw = costL + (((w << 6) + lane) << 3);
        unsigned long long o = 0ull;
#pragma unroll
        for (int k = 0; k < 8; k++) o |= rw[k];
        unsigned long long bal = __ballot(o != 0ull);
        if (lane == 0) rows_nz[w] = bal;
    }
    __syncthreads();

    if (lane == 0) {
        unsigned long long freeb[8];
#pragma unroll
        for (int k = 0; k < 8; k++) freeb[k] = ~0ull;
        bool general = false;
        unsigned long long Znext[8];
#pragma unroll
        for (int k = 0; k < 8; k++) Znext[k] = costL[k];   // row 1 prefetch

        for (int i = 1; i <= NQ; i++) {
            if (!general) {
                unsigned long long ones[8];
#pragma unroll
                for (int k = 0; k < 8; k++) ones[k] = Znext[k];
                if (i < NQ) {
#pragma unroll
                    for (int k = 0; k < 8; k++) Znext[k] = costL[(i << 3) + k];
                }
                bool nzrow = (rows_nz[(i - 1) >> 6] >> ((i - 1) & 63)) & 1ull;
                if (!nzrow) {
                    // all-zero row: reference walk = no-op -> lowest free col
                    int jf = -1;
#pragma unroll
                    for (int k = 0; k < 8; k++)
                        if (jf < 0 && freeb[k] != 0ull) jf = (k << 6) + __builtin_ctzll(freeb[k]);
                    {
                        int wd = jf >> 6; unsigned long long m = 1ull << (jf & 63);
#pragma unroll
                        for (int k = 0; k < 8; k++) if (k == wd) freeb[k] &= ~m;
                    }
                    p[jf + 1] = i;
                    continue;
                }
                unsigned long long vis[8], nzA[8], nzB[8];
#pragma unroll
                for (int k = 0; k < 8; k++) { vis[k] = 0ull; nzA[k] = 0ull; nzB[k] = 0ull; }
                int fA_c = 0, fA_p = 0, fB_c = 0, fB_p = 0;
                int foldn = 0, assignTo = -1;
                bool bail = false;
                while (true) {
                    int c = -1;
#pragma unroll
                    for (int k = 0; k < 8; k++) {
                        unsigned long long s = ~ones[k] & ~vis[k];
                        if (c < 0 && s != 0ull) c = (k << 6) + __builtin_ctzll(s);
                    }
                    if (c < 0) { bail = true; break; }   // delta>0 needed
                    bool isfree = false;
                    {
                        int wd = c >> 6; unsigned long long m = 1ull << (c & 63);
#pragma unroll
                        for (int k = 0; k < 8; k++) if (k == wd) isfree = (freeb[k] & m) != 0ull;
                    }
                    if (isfree) { assignTo = c; break; }
                    int pc = p[c + 1];                       // LDS
                    unsigned long long Zo[8];
#pragma unroll
                    for (int k = 0; k < 8; k++) Zo[k] = costL[((pc - 1) << 3) + k];
                    {
                        int wd = c >> 6; unsigned long long m = 1ull << (c & 63);
#pragma unroll
                        for (int k = 0; k < 8; k++) if (k == wd) vis[k] |= m;
                    }
                    unsigned long long nz[8], ap = 0ull;
#pragma unroll
                    for (int k = 0; k < 8; k++) {
                        nz[k] = ones[k] & ~Zo[k];
                        ones[k] &= Zo[k];
                        ap |= ones[k];
                    }
                    if (foldn == 0) {
                        fA_c = c; fA_p = pc;
#pragma unroll
                        for (int k = 0; k < 8; k++) nzA[k] = nz[k];
                    } else if (foldn == 1) {
                        fB_c = c; fB_p = pc;
#pragma unroll
                        for (int k = 0; k < 8; k++) nzB[k] = nz[k];
                    } else {
#pragma unroll
                        for (int k = 0; k < 8; k++) {
                            unsigned long long tt = nz[k];
                            while (tt) {
                                int b2 = __builtin_ctzll(tt); tt &= tt - 1;
                                wayL[(k << 6) + b2 + 1] = (i << 10) | (c + 1);
                            }
                        }
                    }
                    foldn++;
                    if (ap == 0ull) {
                        // shortcut: rest of walk is a provable no-op
                        int jf = -1;
#pragma unroll
                        for (int k = 0; k < 8; k++)
                            if (jf < 0 && freeb[k] != 0ull) jf = (k << 6) + __builtin_ctzll(freeb[k]);
                        assignTo = jf;
                        break;
                    }
                }
                if (!bail) {
                    {
                        int wd = assignTo >> 6; unsigned long long m = 1ull << (assignTo & 63);
#pragma unroll
                        for (int k = 0; k < 8; k++) if (k == wd) freeb[k] &= ~m;
                    }
                    int cc = assignTo;
                    while (true) {
                        bool inA = false, inB = false;
                        {
                            int wd = cc >> 6; unsigned long long m = 1ull << (cc & 63);
#pragma unroll
                            for (int k = 0; k < 8; k++)
                                if (k == wd) { inA = (nzA[k] & m) != 0ull; inB = (nzB[k] & m) != 0ull; }
                        }
                        if (inB)      { p[cc + 1] = fB_p; cc = fB_c; }
                        else if (inA) { p[cc + 1] = fA_p; cc = fA_c; }
                        else if (foldn > 2) {
                            int wv = wayL[cc + 1];
                            if ((wv >> 10) == i) { int jn = wv & 1023; p[cc + 1] = p[jn]; cc = jn - 1; }
                            else                 { p[cc + 1] = i; break; }
                        } else { p[cc + 1] = i; break; }
                    }
                    continue;
                }
                general = true;   // fall through to general JV for this row
            }
            // fully general integer JV (exact reference semantics); iter-1
            // rewrites way for every unused column -> stale tags cannot leak.
            p[0] = i;
            for (int j = 0; j <= NQ; j++) { minvA[j] = 0x7fffffff; used[j] = 0; }
            int j0 = 0;
            while (true) {
                used[j0] = 1;
                int i0 = p[j0];
                int ui0 = u[i0];
                const unsigned long long* rr = costL + ((size_t)(i0 - 1) << 3);
                int delta = 0x7fffffff, j1 = 0;
                for (int j = 1; j <= NQ; j++) {
                    if (!used[j]) {
                        int cbit = (int)((rr[(j - 1) >> 6] >> ((j - 1) & 63)) & 1ull);
                        int cur = cbit - ui0 - vv[j];
                        if (cur < minvA[j]) { minvA[j] = cur; wayL[j] = (i << 10) | j0; }
                        if (minvA[j] < delta) { delta = minvA[j]; j1 = j; }
                    }
                }
                for (int j = 0; j <= NQ; j++) {
                    if (used[j]) { u[p[j]] += delta; vv[j] -= delta; }
                    else minvA[j] -= delta;
                }
                j0 = j1;
                if (p[j0] == 0) break;
            }
            while (j0) {
                int wv = wayL[j0];
                int jn = ((wv >> 10) == i) ? (wv & 1023) : 0;
                p[j0] = p[jn];
                j0 = jn;
            }
        }
    }
    __syncthreads();

    // Fused CIoU epilogue: p is a permutation, so summing over columns j
    // (curr idx j-1, filtered idx p[j]-1) == summing over rows.
    {
#pragma clang fp contract(off)
        float H = image_sizes[2 * b + 0];
        float W = image_sizes[2 * b + 1];
        float sum = 0.f;
#pragma unroll
        for (int k = 0; k < 8; k++) {
            int j = 1 + lane + (k << 6);
            int r = p[j] - 1;     // filtered row
            int c = j - 1;        // curr box index
            float4 cb = ((const float4*)curr_boxes)[(b << 9) + c];
            float x1 = cb.x - 0.5f * cb.z, y1 = cb.y - 0.5f * cb.w;
            float x2 = cb.x + 0.5f * cb.z, y2 = cb.y + 0.5f * cb.w;
            float4 pb = ((const float4*)prev_boxes)[(b << 9) + r];
            float fcx = (pb.x * W) / W, fcy = (pb.y * H) / H;
            float fw  = (pb.z * W) / W, fh  = (pb.w * H) / H;
            float xg1 = fcx - 0.5f * fw, yg1 = fcy - 0.5f * fh;
            float xg2 = fcx + 0.5f * fw, yg2 = fcy + 0.5f * fh;
            float iw = fmaxf(fminf(x2, xg2) - fmaxf(x1, xg1), 0.f);
            float ih = fmaxf(fminf(y2, yg2) - fmaxf(y1, yg1), 0.f);
            float inter = iw * ih;
            float uni = (x2 - x1) * (y2 - y1) + (xg2 - xg1) * (yg2 - yg1) - inter;
            float iou = inter / (uni + 1e-7f);
            float cw = fmaxf(x2, xg2) - fminf(x1, xg1);
            float ch = fmaxf(y2, yg2) - fminf(y1, yg1);
            float c2 = cw * cw + ch * ch + 1e-7f;
            float dx = ((x1 + x2) - xg1) - xg2;
            float dy = ((y1 + y2) - yg1) - yg2;
            float d2 = (dx * dx + dy * dy) / 4.f;
            const float CC = (float)(4.0 / (M_PI * M_PI));
            float at = atanf((xg2 - xg1) / (yg2 - yg1)) - atanf((x2 - x1) / (y2 - y1));
            float v = CC * (at * at);
            float alpha = v / (((1.f - iou) + v) + 1e-7f);
            sum += ((1.f - iou) + d2 / c2) + alpha * v;
        }
#pragma unroll
        for (int off = 32; off >= 1; off >>= 1) sum += __shfl_xor(sum, off, 64);
        if (lane == 0) atomicAdd(out, sum * (1.f / 4096.f));
    }
}

extern "C" void kernel_launch(void* const* d_in, const int* in_sizes, int n_in,
                              void* d_out, int out_size, void* d_ws, size_t ws_size,
                              hipStream_t stream) {
    const float* prev_boxes  = (const float*)d_in[0];
    // d_in[1] = prev_logits : dead code (Kalman innovation == 0 exactly)
    const float* curr_boxes  = (const float*)d_in[2];
    const float* image_sizes = (const float*)d_in[3];
    // d_in[4..6] (std weights, log_q_diag) : dead code

    unsigned long long* cost = (unsigned long long*)d_ws;
    float* out = (float*)d_out;

    cost_kernel<<<(NB * NQ * NQ) / 256, 256, 0, stream>>>(
        prev_boxes, curr_boxes, image_sizes, cost, out);
    hungarian_kernel<<<NB, 64, 0, stream>>>(
        cost, prev_boxes, curr_boxes, image_sizes, out);
}

// Round 6
// 217.451 us; speedup vs baseline: 2.2457x; 1.4818x over previous
//
#include <hip/hip_runtime.h>
#include <stdint.h>
#include <math.h>

#define NB 8
#define NQ 512

typedef unsigned long long u64;

// ws layout (bytes):
//   [0) cost bits : NB*NQ*8 u64 = 262144  (bit l of word k of row i = cost[i][64k+l])

// Fused prep+cost: xyxy conversions inline (bit-identical to reference:
// Kalman innovation == 0 exactly, so filtered = (prev*scale)/scale).
__global__ void cost_kernel(const float* __restrict__ prev_boxes,
                            const float* __restrict__ curr_boxes,
                            const float* __restrict__ image_sizes,
                            u64* __restrict__ cost,
                            float* __restrict__ out) {
#pragma clang fp contract(off)
    int t = blockIdx.x * blockDim.x + threadIdx.x;   // 0 .. NB*NQ*NQ-1
    if (t == 0) out[0] = 0.f;
    int b = t >> 18;
    int rem = t & (NQ * NQ - 1);
    int i = rem >> 9;        // row: curr box
    int j = rem & (NQ - 1);  // col: filtered box
    float4 cb = ((const float4*)curr_boxes)[(b << 9) + i];
    float ax = cb.x - 0.5f * cb.z, ay = cb.y - 0.5f * cb.w;
    float az = cb.x + 0.5f * cb.z, aw = cb.y + 0.5f * cb.w;
    float H = image_sizes[2 * b + 0];
    float W = image_sizes[2 * b + 1];
    float4 pb = ((const float4*)prev_boxes)[(b << 9) + j];
    float fcx = (pb.x * W) / W, fcy = (pb.y * H) / H;
    float fw  = (pb.z * W) / W, fh  = (pb.w * H) / H;
    float bx = fcx - 0.5f * fw, by = fcy - 0.5f * fh;
    float bz = fcx + 0.5f * fw, bw = fcy + 0.5f * fh;
    float area_a = (az - ax) * (aw - ay);
    float area_b = (bz - bx) * (bw - by);
    float ltx = fmaxf(ax, bx), lty = fmaxf(ay, by);
    float rbx = fminf(az, bz), rby = fminf(aw, bw);
    float w = fmaxf(rbx - ltx, 0.f), h = fmaxf(rby - lty, 0.f);
    float inter = w * h;
    float uni = area_a + area_b - inter;
    float iou = inter / (uni + 1e-7f);
    float lcx = fminf(ax, bx), lcy = fminf(ay, by);
    float rcx = fmaxf(az, bz), rcy = fmaxf(aw, bw);
    float wc = fmaxf(rcx - lcx, 0.f), hc = fmaxf(rcy - lcy, 0.f);
    float areac = wc * hc;
    float giou = iou - (areac - uni) / (areac + 1e-7f);
    float gl = 1.f - giou;
    u64 m = __ballot(gl < 0.2f);
    if ((threadIdx.x & 63) == 0)
        cost[((size_t)((b << 9) + i)) * 8 + (j >> 6)] = m;
}

// Exact integer replication of the reference JV Hungarian on a {0,1} cost
// matrix + fused CIoU epilogue. Lane-0 serial loop, cost staged in LDS.
// R5 lesson: the serial chain is dependent-VALU-latency bound (~4 cy/instr),
// so the hot (all-zero-row) path must be minimal: rows_nz kept in a register
// word (2 instr/row test), lowest-free-column kept as an incremental
// (cw, fw) cursor (pop = ctz + and, ~4 instr) — valid because zero rows and
// shortcut-assigns always consume the lowest free column (monotone), and
// direct-candidate assigns only punch holes ABOVE the cursor. freeb[] array
// stays authoritative for words != cw (select-trick access, rare paths only).
// Any delta>0 event bails to the exact general integer JV (sticky).
__global__ __launch_bounds__(64, 1) void hungarian_kernel(
        const u64* __restrict__ cost,
        const float* __restrict__ prev_boxes,
        const float* __restrict__ curr_boxes,
        const float* __restrict__ image_sizes,
        float* __restrict__ out) {
    int b = blockIdx.x;
    int lane = threadIdx.x;
    __shared__ __align__(16) u64 costL[NQ * 8];   // 32 KB
    __shared__ int p[NQ + 1];
    __shared__ int wayL[NQ + 1];
    __shared__ int u[NQ + 1];
    __shared__ int vv[NQ + 1];
    __shared__ int minvA[NQ + 1];
    __shared__ unsigned char used[NQ + 1];
    __shared__ u64 rows_nz_sh[8];

    {
        const ulonglong2* src = (const ulonglong2*)(cost + (size_t)b * NQ * 8);
        ulonglong2* dst = (ulonglong2*)costL;
        for (int k = lane; k < NQ * 4; k += 64) dst[k] = src[k];
    }
    for (int k = lane; k <= NQ; k += 64) { p[k] = 0; wayL[k] = 0; u[k] = 0; vv[k] = 0; }
    __syncthreads();
    for (int w = 0; w < 8; w++) {
        const u64* rw = costL + (((w << 6) + lane) << 3);
        u64 o = 0ull;
#pragma unroll
        for (int k = 0; k < 8; k++) o |= rw[k];
        u64 bal = __ballot(o != 0ull);
        if (lane == 0) rows_nz_sh[w] = bal;
    }
    __syncthreads();

    if (lane == 0) {
        u64 freeb[8];
#pragma unroll
        for (int k = 0; k < 8; k++) freeb[k] = ~0ull;
        int cw = 0;          // cursor word; live value of freeb[cw] is fw
        u64 fw = ~0ull;
        bool general = false;
        int i = 0;
        for (int w = 0; w < 8; w++) {
            u64 nzw = rows_nz_sh[w];
            for (int bb = 0; bb < 64; bb++) {
                i++;
                u64 rowbit = nzw & 1ull;
                nzw >>= 1;
                if (!general) {
                    if (!rowbit) {
                        // all-zero row: reference walk assigns lowest free col
                        int jf = (cw << 6) + __builtin_ctzll(fw);
                        fw &= fw - 1;
                        while (fw == 0ull && cw < 7) {
#pragma unroll
                            for (int k = 0; k < 8; k++) if (k == cw) freeb[k] = 0ull;
                            cw++;
#pragma unroll
                            for (int k = 0; k < 8; k++) if (k == cw) fw = freeb[k];
                        }
                        p[jf + 1] = i;
                        continue;
                    }
                    // nonzero row: bitset search with zero duals
                    u64 ones[8], vis[8], nzA[8], nzB[8];
#pragma unroll
                    for (int k = 0; k < 8; k++) {
                        ones[k] = costL[((i - 1) << 3) + k];
                        vis[k] = 0ull; nzA[k] = 0ull; nzB[k] = 0ull;
                    }
                    int fA_c = 0, fA_p = 0, fB_c = 0, fB_p = 0;
                    int foldn = 0, assignTo = -1;
                    bool bail = false;
                    while (true) {
                        int c = -1;
#pragma unroll
                        for (int k = 0; k < 8; k++) {
                            u64 s = ~ones[k] & ~vis[k];
                            if (c < 0 && s != 0ull) c = (k << 6) + __builtin_ctzll(s);
                        }
                        if (c < 0) { bail = true; break; }   // delta>0 needed
                        int wd = c >> 6;
                        u64 fword = 0ull;
#pragma unroll
                        for (int k = 0; k < 8; k++) if (k == wd) fword = freeb[k];
                        if (wd == cw) fword = fw;
                        if ((fword >> (c & 63)) & 1ull) { assignTo = c; break; }  // free
                        int pc = p[c + 1];                       // LDS
                        u64 Zo[8];
#pragma unroll
                        for (int k = 0; k < 8; k++) Zo[k] = costL[((pc - 1) << 3) + k];
                        {
                            u64 m = 1ull << (c & 63);
#pragma unroll
                            for (int k = 0; k < 8; k++) if (k == wd) vis[k] |= m;
                        }
                        u64 nz[8], ap = 0ull;
#pragma unroll
                        for (int k = 0; k < 8; k++) {
                            nz[k] = ones[k] & ~Zo[k];
                            ones[k] &= Zo[k];
                            ap |= ones[k];
                        }
                        if (foldn == 0) {
                            fA_c = c; fA_p = pc;
#pragma unroll
                            for (int k = 0; k < 8; k++) nzA[k] = nz[k];
                        } else if (foldn == 1) {
                            fB_c = c; fB_p = pc;
#pragma unroll
                            for (int k = 0; k < 8; k++) nzB[k] = nz[k];
                        } else {
#pragma unroll
                            for (int k = 0; k < 8; k++) {
                                u64 tt = nz[k];
                                while (tt) {
                                    int b2 = __builtin_ctzll(tt); tt &= tt - 1;
                                    wayL[(k << 6) + b2 + 1] = (i << 10) | (c + 1);
                                }
                            }
                        }
                        foldn++;
                        if (ap == 0ull) {
                            // shortcut: rest of walk is a provable no-op
                            assignTo = (cw << 6) + __builtin_ctzll(fw);
                            break;
                        }
                    }
                    if (!bail) {
                        // consume assignTo from the free structure
                        int wd = assignTo >> 6;
                        u64 m = 1ull << (assignTo & 63);
                        if (wd == cw) {
                            fw &= ~m;
                            while (fw == 0ull && cw < 7) {
#pragma unroll
                                for (int k = 0; k < 8; k++) if (k == cw) freeb[k] = 0ull;
                                cw++;
#pragma unroll
                                for (int k = 0; k < 8; k++) if (k == cw) fw = freeb[k];
                            }
                        } else {
#pragma unroll
                            for (int k = 0; k < 8; k++) if (k == wd) freeb[k] &= ~m;
                        }
                        // augment via register fold records (each column in
                        // at most one fold's nz set)
                        int cc = assignTo;
                        while (true) {
                            bool inA = false, inB = false;
                            {
                                int wd2 = cc >> 6; u64 m2 = 1ull << (cc & 63);
#pragma unroll
                                for (int k = 0; k < 8; k++)
                                    if (k == wd2) { inA = (nzA[k] & m2) != 0ull; inB = (nzB[k] & m2) != 0ull; }
                            }
                            if (inB)      { p[cc + 1] = fB_p; cc = fB_c; }
                            else if (inA) { p[cc + 1] = fA_p; cc = fA_c; }
                            else if (foldn > 2) {
                                int wv = wayL[cc + 1];
                                if ((wv >> 10) == i) { int jn = wv & 1023; p[cc + 1] = p[jn]; cc = jn - 1; }
                                else                 { p[cc + 1] = i; break; }
                            } else { p[cc + 1] = i; break; }
                        }
                        continue;
                    }
                    general = true;   // fall through to general JV for this row
                }
                // fully general integer JV (exact reference semantics); iter-1
                // rewrites way for every unused column -> stale tags can't leak.
                p[0] = i;
                for (int j = 0; j <= NQ; j++) { minvA[j] = 0x7fffffff; used[j] = 0; }
                int j0 = 0;
                while (true) {
                    used[j0] = 1;
                    int i0 = p[j0];
                    int ui0 = u[i0];
                    const u64* rr = costL + ((size_t)(i0 - 1) << 3);
                    int delta = 0x7fffffff, j1 = 0;
                    for (int j = 1; j <= NQ; j++) {
                        if (!used[j]) {
                            int cbit = (int)((rr[(j - 1) >> 6] >> ((j - 1) & 63)) & 1ull);
                            int cur = cbit - ui0 - vv[j];
                            if (cur < minvA[j]) { minvA[j] = cur; wayL[j] = (i << 10) | j0; }
                            if (minvA[j] < delta) { delta = minvA[j]; j1 = j; }
                        }
                    }
                    for (int j = 0; j <= NQ; j++) {
                        if (used[j]) { u[p[j]] += delta; vv[j] -= delta; }
                        else minvA[j] -= delta;
                    }
                    j0 = j1;
                    if (p[j0] == 0) break;
                }
                while (j0) {
                    int wv = wayL[j0];
                    int jn = ((wv >> 10) == i) ? (wv & 1023) : 0;
                    p[j0] = p[jn];
                    j0 = jn;
                }
            }
        }
    }
    __syncthreads();

    // Fused CIoU epilogue: p is a permutation, so summing over columns j
    // (curr idx j-1, filtered idx p[j]-1) == summing over rows.
    {
#pragma clang fp contract(off)
        float H = image_sizes[2 * b + 0];
        float W = image_sizes[2 * b + 1];
        float sum = 0.f;
#pragma unroll
        for (int k = 0; k < 8; k++) {
            int j = 1 + lane + (k << 6);
            int r = p[j] - 1;     // filtered row
            int c = j - 1;        // curr box index
            float4 cb = ((const float4*)curr_boxes)[(b << 9) + c];
            float x1 = cb.x - 0.5f * cb.z, y1 = cb.y - 0.5f * cb.w;
            float x2 = cb.x + 0.5f * cb.z, y2 = cb.y + 0.5f * cb.w;
            float4 pb = ((const float4*)prev_boxes)[(b << 9) + r];
            float fcx = (pb.x * W) / W, fcy = (pb.y * H) / H;
            float fw2 = (pb.z * W) / W, fh2 = (pb.w * H) / H;
            float xg1 = fcx - 0.5f * fw2, yg1 = fcy - 0.5f * fh2;
            float xg2 = fcx + 0.5f * fw2, yg2 = fcy + 0.5f * fh2;
            float iw = fmaxf(fminf(x2, xg2) - fmaxf(x1, xg1), 0.f);
            float ih = fmaxf(fminf(y2, yg2) - fmaxf(y1, yg1), 0.f);
            float inter = iw * ih;
            float uni = (x2 - x1) * (y2 - y1) + (xg2 - xg1) * (yg2 - yg1) - inter;
            float iou = inter / (uni + 1e-7f);
            float cw2 = fmaxf(x2, xg2) - fminf(x1, xg1);
            float ch2 = fmaxf(y2, yg2) - fminf(y1, yg1);
            float c2 = cw2 * cw2 + ch2 * ch2 + 1e-7f;
            float dx = ((x1 + x2) - xg1) - xg2;
            float dy = ((y1 + y2) - yg1) - yg2;
            float d2 = (dx * dx + dy * dy) / 4.f;
            const float CC = (float)(4.0 / (M_PI * M_PI));
            float at = atanf((xg2 - xg1) / (yg2 - yg1)) - atanf((x2 - x1) / (y2 - y1));
            float v = CC * (at * at);
            float alpha = v / (((1.f - iou) + v) + 1e-7f);
            sum += ((1.f - iou) + d2 / c2) + alpha * v;
        }
#pragma unroll
        for (int off = 32; off >= 1; off >>= 1) sum += __shfl_xor(sum, off, 64);
        if (lane == 0) atomicAdd(out, sum * (1.f / 4096.f));
    }
}

extern "C" void kernel_launch(void* const* d_in, const int* in_sizes, int n_in,
                              void* d_out, int out_size, void* d_ws, size_t ws_size,
                              hipStream_t stream) {
    const float* prev_boxes  = (const float*)d_in[0];
    // d_in[1] = prev_logits : dead code (Kalman innovation == 0 exactly)
    const float* curr_boxes  = (const float*)d_in[2];
    const float* image_sizes = (const float*)d_in[3];
    // d_in[4..6] (std weights, log_q_diag) : dead code

    u64* cost = (u64*)d_ws;
    float* out = (float*)d_out;

    cost_kernel<<<(NB * NQ * NQ) / 256, 256, 0, stream>>>(
        prev_boxes, curr_boxes, image_sizes, cost, out);
    hungarian_kernel<<<NB, 64, 0, stream>>>(
        cost, prev_boxes, curr_boxes, image_sizes, out);
}

// Round 7
// 168.239 us; speedup vs baseline: 2.9026x; 1.2925x over previous
//
#include <hip/hip_runtime.h>
#include <stdint.h>
#include <math.h>

#define NB 8
#define NQ 512

typedef unsigned long long u64;

// ws layout (bytes):
//   [0) cost bits : NB*NQ*8 u64 = 262144  (bit l of word k of row i = cost[i][64k+l])

// ---- register-array helpers: constant-index-only access (no scratch spills) ----
__device__ __forceinline__ u64 getw8(const u64 (&a)[8], int w) {
    u64 r = 0ull;
#pragma unroll
    for (int k = 0; k < 8; k++) if (k == w) r = a[k];
    return r;
}
__device__ __forceinline__ void setw8(u64 (&a)[8], int w, u64 v) {
#pragma unroll
    for (int k = 0; k < 8; k++) if (k == w) a[k] = v;
}
__device__ __forceinline__ bool getbit8(const u64 (&a)[8], int c) {
    return (getw8(a, c >> 6) >> (c & 63)) & 1ull;
}
__device__ __forceinline__ void setbit8(u64 (&a)[8], int c) {
    int w = c >> 6; u64 m = 1ull << (c & 63);
#pragma unroll
    for (int k = 0; k < 8; k++) if (k == w) a[k] |= m;
}
__device__ __forceinline__ void clrbit8(u64 (&a)[8], int c) {
    int w = c >> 6; u64 m = ~(1ull << (c & 63));
#pragma unroll
    for (int k = 0; k < 8; k++) if (k == w) a[k] &= m;
}

// Fused prep+cost: xyxy conversions inline (bit-identical to reference:
// Kalman innovation == 0 exactly, so filtered = (prev*scale)/scale).
__global__ void cost_kernel(const float* __restrict__ prev_boxes,
                            const float* __restrict__ curr_boxes,
                            const float* __restrict__ image_sizes,
                            u64* __restrict__ cost,
                            float* __restrict__ out) {
#pragma clang fp contract(off)
    int t = blockIdx.x * blockDim.x + threadIdx.x;   // 0 .. NB*NQ*NQ-1
    if (t == 0) out[0] = 0.f;
    int b = t >> 18;
    int rem = t & (NQ * NQ - 1);
    int i = rem >> 9;        // row: curr box
    int j = rem & (NQ - 1);  // col: filtered box
    float4 cb = ((const float4*)curr_boxes)[(b << 9) + i];
    float ax = cb.x - 0.5f * cb.z, ay = cb.y - 0.5f * cb.w;
    float az = cb.x + 0.5f * cb.z, aw = cb.y + 0.5f * cb.w;
    float H = image_sizes[2 * b + 0];
    float W = image_sizes[2 * b + 1];
    float4 pb = ((const float4*)prev_boxes)[(b << 9) + j];
    float fcx = (pb.x * W) / W, fcy = (pb.y * H) / H;
    float fw  = (pb.z * W) / W, fh  = (pb.w * H) / H;
    float bx = fcx - 0.5f * fw, by = fcy - 0.5f * fh;
    float bz = fcx + 0.5f * fw, bw = fcy + 0.5f * fh;
    float area_a = (az - ax) * (aw - ay);
    float area_b = (bz - bx) * (bw - by);
    float ltx = fmaxf(ax, bx), lty = fmaxf(ay, by);
    float rbx = fminf(az, bz), rby = fminf(aw, bw);
    float w = fmaxf(rbx - ltx, 0.f), h = fmaxf(rby - lty, 0.f);
    float inter = w * h;
    float uni = area_a + area_b - inter;
    float iou = inter / (uni + 1e-7f);
    float lcx = fminf(ax, bx), lcy = fminf(ay, by);
    float rcx = fmaxf(az, bz), rcy = fmaxf(aw, bw);
    float wc = fmaxf(rcx - lcx, 0.f), hc = fmaxf(rcy - lcy, 0.f);
    float areac = wc * hc;
    float giou = iou - (areac - uni) / (areac + 1e-7f);
    float gl = 1.f - giou;
    u64 m = __ballot(gl < 0.2f);
    if ((threadIdx.x & 63) == 0)
        cost[((size_t)((b << 9) + i)) * 8 + (j >> 6)] = m;
}

// Exact integer replication of the reference JV Hungarian on a {0,1} cost
// matrix + fused CIoU epilogue. Lane-0 serial loop, cost staged in LDS.
// R6 lesson: nonzero rows (~60%) each paid 3 dependent LDS round-trips.
// R7: ownerNZ register bitset (cols owned by nonzero rows) makes the
// owner-zero fold read-free; a 1-entry register cache of the poisoned
// column's owner row makes the owner-nonzero fold read-free; next nonzero
// row's bits are prefetched one row ahead. Slow path (multi-fold) and the
// exact general integer JV fallback (sticky on any delta>0) are retained.
__global__ __launch_bounds__(64, 1) void hungarian_kernel(
        const u64* __restrict__ cost,
        const float* __restrict__ prev_boxes,
        const float* __restrict__ curr_boxes,
        const float* __restrict__ image_sizes,
        float* __restrict__ out) {
    int b = blockIdx.x;
    int lane = threadIdx.x;
    __shared__ __align__(16) u64 costL[NQ * 8];   // 32 KB
    __shared__ int p[NQ + 1];
    __shared__ int wayL[NQ + 1];
    __shared__ int u[NQ + 1];
    __shared__ int vv[NQ + 1];
    __shared__ int minvA[NQ + 1];
    __shared__ unsigned char used[NQ + 1];
    __shared__ u64 rows_nz_sh[8];

    {
        const ulonglong2* src = (const ulonglong2*)(cost + (size_t)b * NQ * 8);
        ulonglong2* dst = (ulonglong2*)costL;
        for (int k = lane; k < NQ * 4; k += 64) dst[k] = src[k];
    }
    for (int k = lane; k <= NQ; k += 64) { p[k] = 0; wayL[k] = 0; u[k] = 0; vv[k] = 0; }
    __syncthreads();
    for (int w = 0; w < 8; w++) {
        const u64* rw = costL + (((w << 6) + lane) << 3);
        u64 o = 0ull;
#pragma unroll
        for (int k = 0; k < 8; k++) o |= rw[k];
        u64 bal = __ballot(o != 0ull);
        if (lane == 0) rows_nz_sh[w] = bal;
    }
    __syncthreads();

    if (lane == 0) {
        u64 rnz[8];
#pragma unroll
        for (int k = 0; k < 8; k++) rnz[k] = rows_nz_sh[k];
        u64 freeb[8];
#pragma unroll
        for (int k = 0; k < 8; k++) freeb[k] = ~0ull;
        int cw = 0; u64 fw = ~0ull;          // cursor: lowest free col
        u64 ownerNZ[8];
#pragma unroll
        for (int k = 0; k < 8; k++) ownerNZ[k] = 0ull;
        int cacheCol = -1, cacheP = 1;
        u64 cacheRow[8];
#pragma unroll
        for (int k = 0; k < 8; k++) cacheRow[k] = 0ull;
        bool general = false;
        int igen = NQ + 1;

        int rwIdx = 0; u64 rbits = rnz[0];   // rolling nonzero-row cursor
        auto nextNZ = [&]() -> int {
            while (rbits == 0ull && rwIdx < 7) {
                rwIdx++;
#pragma unroll
                for (int k = 0; k < 8; k++) if (k == rwIdx) rbits = rnz[k];
            }
            if (rbits == 0ull) return NQ;
            int r = (rwIdx << 6) + __builtin_ctzll(rbits);
            rbits &= rbits - 1;
            return r;
        };
        auto popCursor = [&]() -> int {
            int jf = (cw << 6) + __builtin_ctzll(fw);
            fw &= fw - 1;
            while (fw == 0ull && cw < 7) { setw8(freeb, cw, 0ull); cw++; fw = getw8(freeb, cw); }
            return jf;
        };
        auto consumeCol = [&](int col) {
            int wd = col >> 6; u64 m = 1ull << (col & 63);
            if (wd == cw) {
                fw &= ~m;
                while (fw == 0ull && cw < 7) { setw8(freeb, cw, 0ull); cw++; fw = getw8(freeb, cw); }
            } else {
#pragma unroll
                for (int k = 0; k < 8; k++) if (k == wd) freeb[k] &= ~m;
            }
        };

        int cur = nextNZ();
        u64 Zp[8];
        if (cur < NQ) {
#pragma unroll
            for (int k = 0; k < 8; k++) Zp[k] = costL[(cur << 3) + k];
        }
        int done = 0;    // 0-based rows completed
        while (true) {
            int upto = (cur < NQ) ? cur : NQ;
            for (int r = done; r < upto; r++) {       // zero rows: lowest free col
                int jf = popCursor();
                p[jf + 1] = r + 1;
            }
            done = upto;
            if (cur >= NQ) break;
            int i = cur + 1;                          // 1-based row
            int jf0 = (cw << 6) + __builtin_ctzll(fw);  // cursor head (shortcut target)
            // early LDS reads for membership bits (addresses known now)
            u64 mw1 = costL[((i - 1) << 3) + (jf0 >> 6)];
            u64 mw2 = costL[((cacheP - 1) << 3) + (jf0 >> 6)];
            u64 Z[8];
#pragma unroll
            for (int k = 0; k < 8; k++) Z[k] = Zp[k];
            int nxt = nextNZ();
            if (nxt < NQ) {
#pragma unroll
                for (int k = 0; k < 8; k++) Zp[k] = costL[(nxt << 3) + k];
            }
            // candidate c = first zero-cost column
            int c;
            u64 inv0 = ~Z[0];
            if (inv0 != 0ull) c = __builtin_ctzll(inv0);
            else {
                c = -1;
#pragma unroll
                for (int k = 7; k >= 1; k--) { u64 s = ~Z[k]; if (s != 0ull) c = (k << 6) + __builtin_ctzll(s); }
            }
            bool needSlow = false, bail = false;
            if (c < 0) bail = true;                   // row all ones: delta>0 needed
            else {
                int wd = c >> 6;
                u64 fword = getw8(freeb, wd);
                if (wd == cw) fword = fw;
                if ((fword >> (c & 63)) & 1ull) {
                    // candidate free: direct assign
                    consumeCol(c);
                    p[c + 1] = i;
                    setbit8(ownerNZ, c);
                    cacheCol = c; cacheP = i;
#pragma unroll
                    for (int k = 0; k < 8; k++) cacheRow[k] = Z[k];
                } else if (!getbit8(ownerNZ, c)) {
                    // owner is a zero row: fold -> ones=0 -> shortcut to cursor
                    bool memb = (mw1 >> (jf0 & 63)) & 1ull;   // cost[i][jf0]
                    popCursor();                              // consumes jf0
                    if (!memb) {
                        p[jf0 + 1] = i;
                        setbit8(ownerNZ, jf0);
                    } else {
                        int oldo = p[c + 1];                  // rare LDS read
                        p[jf0 + 1] = oldo;                    // zero row relocated
                        p[c + 1] = i;
                        setbit8(ownerNZ, c);
                        cacheCol = c; cacheP = i;
#pragma unroll
                        for (int k = 0; k < 8; k++) cacheRow[k] = Z[k];
                    }
                } else if (c == cacheCol) {
                    // owner nonzero, cached: register fold
                    u64 ap = 0ull;
#pragma unroll
                    for (int k = 0; k < 8; k++) ap |= Z[k] & cacheRow[k];
                    if (ap != 0ull) needSlow = true;          // multi-visit
                    else {
                        bool zb = (mw1 >> (jf0 & 63)) & 1ull;
                        bool ob = (mw2 >> (jf0 & 63)) & 1ull; // cacheRow bit jf0
                        popCursor();
                        if (zb && !ob) {
                            p[jf0 + 1] = cacheP;              // kick nonzero owner
                            setbit8(ownerNZ, jf0);
                            p[c + 1] = i;
                            cacheP = i;
#pragma unroll
                            for (int k = 0; k < 8; k++) cacheRow[k] = Z[k];
                        } else {
                            p[jf0 + 1] = i;
                            setbit8(ownerNZ, jf0);
                        }
                    }
                } else needSlow = true;
            }
            if (needSlow) {
                // full bitset search (zero duals), restart row from scratch
                u64 ones[8], vis[8], nzA[8], nzB[8];
#pragma unroll
                for (int k = 0; k < 8; k++) { ones[k] = Z[k]; vis[k] = 0ull; nzA[k] = 0ull; nzB[k] = 0ull; }
                int fA_c = 0, fA_p = 0, fB_c = 0, fB_p = 0;
                int foldn = 0, assignTo = -1;
                while (true) {
                    int cc2 = -1;
#pragma unroll
                    for (int k = 7; k >= 0; k--) { u64 s = ~ones[k] & ~vis[k]; if (s != 0ull) cc2 = (k << 6) + __builtin_ctzll(s); }
                    if (cc2 < 0) { bail = true; break; }      // delta>0 needed
                    int wd2 = cc2 >> 6;
                    u64 fword2 = getw8(freeb, wd2);
                    if (wd2 == cw) fword2 = fw;
                    if ((fword2 >> (cc2 & 63)) & 1ull) { assignTo = cc2; break; }
                    int pc = p[cc2 + 1];
                    u64 Zo[8];
#pragma unroll
                    for (int k = 0; k < 8; k++) Zo[k] = costL[((pc - 1) << 3) + k];
                    setbit8(vis, cc2);
                    u64 nzv[8], ap2 = 0ull;
#pragma unroll
                    for (int k = 0; k < 8; k++) { nzv[k] = ones[k] & ~Zo[k]; ones[k] &= Zo[k]; ap2 |= ones[k]; }
                    if (foldn == 0) {
                        fA_c = cc2; fA_p = pc;
#pragma unroll
                        for (int k = 0; k < 8; k++) nzA[k] = nzv[k];
                    } else if (foldn == 1) {
                        fB_c = cc2; fB_p = pc;
#pragma unroll
                        for (int k = 0; k < 8; k++) nzB[k] = nzv[k];
                    } else {
#pragma unroll
                        for (int k = 0; k < 8; k++) {
                            u64 tt = nzv[k];
                            while (tt) { int b2 = __builtin_ctzll(tt); tt &= tt - 1; wayL[(k << 6) + b2 + 1] = (i << 10) | (cc2 + 1); }
                        }
                    }
                    foldn++;
                    if (ap2 == 0ull) { assignTo = (cw << 6) + __builtin_ctzll(fw); break; }
                }
                if (!bail) {
                    consumeCol(assignTo);
                    int cc = assignTo;
                    while (true) {
                        bool inA = getbit8(nzA, cc), inB = getbit8(nzB, cc);
                        if (inB) {
                            p[cc + 1] = fB_p;
                            if (getbit8(ownerNZ, fB_c)) setbit8(ownerNZ, cc); else clrbit8(ownerNZ, cc);
                            cc = fB_c;
                        } else if (inA) {
                            p[cc + 1] = fA_p;
                            if (getbit8(ownerNZ, fA_c)) setbit8(ownerNZ, cc); else clrbit8(ownerNZ, cc);
                            cc = fA_c;
                        } else if (foldn > 2) {
                            int wv = wayL[cc + 1];
                            if ((wv >> 10) == i) {
                                int jn = wv & 1023;
                                p[cc + 1] = p[jn];
                                if (getbit8(ownerNZ, jn - 1)) setbit8(ownerNZ, cc); else clrbit8(ownerNZ, cc);
                                cc = jn - 1;
                            } else { p[cc + 1] = i; setbit8(ownerNZ, cc); break; }
                        } else { p[cc + 1] = i; setbit8(ownerNZ, cc); break; }
                    }
                    // cache rebuild for the candidate col (the future hot col)
                    cacheCol = -1;
                    if (getbit8(ownerNZ, c)) {
                        cacheCol = c; cacheP = p[c + 1];
#pragma unroll
                        for (int k = 0; k < 8; k++) cacheRow[k] = costL[((cacheP - 1) << 3) + k];
                    }
                }
            }
            if (bail) { igen = i; general = true; break; }
            done = i;
            cur = nxt;
        }
        if (general) {
            // exact general integer JV for rows igen..NQ (reference semantics);
            // iter-1 rewrites way for every unused column -> no stale tags.
            for (int i = igen; i <= NQ; i++) {
                p[0] = i;
                for (int j = 0; j <= NQ; j++) { minvA[j] = 0x7fffffff; used[j] = 0; }
                int j0 = 0;
                while (true) {
                    used[j0] = 1;
                    int i0 = p[j0];
                    int ui0 = u[i0];
                    const u64* rr = costL + ((size_t)(i0 - 1) << 3);
                    int delta = 0x7fffffff, j1 = 0;
                    for (int j = 1; j <= NQ; j++) {
                        if (!used[j]) {
                            int cbit = (int)((rr[(j - 1) >> 6] >> ((j - 1) & 63)) & 1ull);
                            int curv = cbit - ui0 - vv[j];
                            if (curv < minvA[j]) { minvA[j] = curv; wayL[j] = (i << 10) | j0; }
                            if (minvA[j] < delta) { delta = minvA[j]; j1 = j; }
                        }
                    }
                    for (int j = 0; j <= NQ; j++) {
                        if (used[j]) { u[p[j]] += delta; vv[j] -= delta; }
                        else minvA[j] -= delta;
                    }
                    j0 = j1;
                    if (p[j0] == 0) break;
                }
                while (j0) {
                    int wv = wayL[j0];
                    int jn = ((wv >> 10) == i) ? (wv & 1023) : 0;
                    p[j0] = p[jn];
                    j0 = jn;
                }
            }
        }
    }
    __syncthreads();

    // Fused CIoU epilogue: p is a permutation, so summing over columns j
    // (curr idx j-1, filtered idx p[j]-1) == summing over rows.
    {
#pragma clang fp contract(off)
        float H = image_sizes[2 * b + 0];
        float W = image_sizes[2 * b + 1];
        float sum = 0.f;
#pragma unroll
        for (int k = 0; k < 8; k++) {
            int j = 1 + lane + (k << 6);
            int r = p[j] - 1;     // filtered row
            int c = j - 1;        // curr box index
            float4 cb = ((const float4*)curr_boxes)[(b << 9) + c];
            float x1 = cb.x - 0.5f * cb.z, y1 = cb.y - 0.5f * cb.w;
            float x2 = cb.x + 0.5f * cb.z, y2 = cb.y + 0.5f * cb.w;
            float4 pb = ((const float4*)prev_boxes)[(b << 9) + r];
            float fcx = (pb.x * W) / W, fcy = (pb.y * H) / H;
            float fw2 = (pb.z * W) / W, fh2 = (pb.w * H) / H;
            float xg1 = fcx - 0.5f * fw2, yg1 = fcy - 0.5f * fh2;
            float xg2 = fcx + 0.5f * fw2, yg2 = fcy + 0.5f * fh2;
            float iw = fmaxf(fminf(x2, xg2) - fmaxf(x1, xg1), 0.f);
            float ih = fmaxf(fminf(y2, yg2) - fmaxf(y1, yg1), 0.f);
            float inter = iw * ih;
            float uni = (x2 - x1) * (y2 - y1) + (xg2 - xg1) * (yg2 - yg1) - inter;
            float iou = inter / (uni + 1e-7f);
            float cw2 = fmaxf(x2, xg2) - fminf(x1, xg1);
            float ch2 = fmaxf(y2, yg2) - fminf(y1, yg1);
            float c2 = cw2 * cw2 + ch2 * ch2 + 1e-7f;
            float dx = ((x1 + x2) - xg1) - xg2;
            float dy = ((y1 + y2) - yg1) - yg2;
            float d2 = (dx * dx + dy * dy) / 4.f;
            const float CC = (float)(4.0 / (M_PI * M_PI));
            float at = atanf((xg2 - xg1) / (yg2 - yg1)) - atanf((x2 - x1) / (y2 - y1));
            float v = CC * (at * at);
            float alpha = v / (((1.f - iou) + v) + 1e-7f);
            sum += ((1.f - iou) + d2 / c2) + alpha * v;
        }
#pragma unroll
        for (int off = 32; off >= 1; off >>= 1) sum += __shfl_xor(sum, off, 64);
        if (lane == 0) atomicAdd(out, sum * (1.f / 4096.f));
    }
}

extern "C" void kernel_launch(void* const* d_in, const int* in_sizes, int n_in,
                              void* d_out, int out_size, void* d_ws, size_t ws_size,
                              hipStream_t stream) {
    const float* prev_boxes  = (const float*)d_in[0];
    // d_in[1] = prev_logits : dead code (Kalman innovation == 0 exactly)
    const float* curr_boxes  = (const float*)d_in[2];
    const float* image_sizes = (const float*)d_in[3];
    // d_in[4..6] (std weights, log_q_diag) : dead code

    u64* cost = (u64*)d_ws;
    float* out = (float*)d_out;

    cost_kernel<<<(NB * NQ * NQ) / 256, 256, 0, stream>>>(
        prev_boxes, curr_boxes, image_sizes, cost, out);
    hungarian_kernel<<<NB, 64, 0, stream>>>(
        cost, prev_boxes, curr_boxes, image_sizes, out);
}

// Round 8
// 91.511 us; speedup vs baseline: 5.3363x; 1.8384x over previous
//
#include <hip/hip_runtime.h>
#include <stdint.h>
#include <math.h>

#define NB 8
#define NQ 512

typedef unsigned long long u64;

// ---- register-array helpers: constant-index-only access (no scratch spills) ----
static __device__ __forceinline__ u64 getw8(const u64 (&a)[8], int w) {
    u64 r = 0ull;
#pragma unroll
    for (int k = 0; k < 8; k++) if (k == w) r = a[k];
    return r;
}
static __device__ __forceinline__ void setbit8(u64 (&a)[8], int c) {
    int w = c >> 6; u64 m = 1ull << (c & 63);
#pragma unroll
    for (int k = 0; k < 8; k++) if (k == w) a[k] |= m;
}
static __device__ __forceinline__ bool getbit8(const u64 (&a)[8], int c) {
    return (getw8(a, c >> 6) >> (c & 63)) & 1ull;
}

// Fused prep+cost: xyxy conversions inline (bit-identical to reference:
// Kalman innovation == 0 exactly, so filtered = (prev*scale)/scale).
__global__ void cost_kernel(const float* __restrict__ prev_boxes,
                            const float* __restrict__ curr_boxes,
                            const float* __restrict__ image_sizes,
                            u64* __restrict__ cost,
                            float* __restrict__ out) {
#pragma clang fp contract(off)
    int t = blockIdx.x * blockDim.x + threadIdx.x;   // 0 .. NB*NQ*NQ-1
    if (t == 0) out[0] = 0.f;
    int b = t >> 18;
    int rem = t & (NQ * NQ - 1);
    int i = rem >> 9;        // row: curr box
    int j = rem & (NQ - 1);  // col: filtered box
    float4 cb = ((const float4*)curr_boxes)[(b << 9) + i];
    float ax = cb.x - 0.5f * cb.z, ay = cb.y - 0.5f * cb.w;
    float az = cb.x + 0.5f * cb.z, aw = cb.y + 0.5f * cb.w;
    float H = image_sizes[2 * b + 0];
    float W = image_sizes[2 * b + 1];
    float4 pb = ((const float4*)prev_boxes)[(b << 9) + j];
    float fcx = (pb.x * W) / W, fcy = (pb.y * H) / H;
    float fw  = (pb.z * W) / W, fh  = (pb.w * H) / H;
    float bx = fcx - 0.5f * fw, by = fcy - 0.5f * fh;
    float bz = fcx + 0.5f * fw, bw = fcy + 0.5f * fh;
    float area_a = (az - ax) * (aw - ay);
    float area_b = (bz - bx) * (bw - by);
    float ltx = fmaxf(ax, bx), lty = fmaxf(ay, by);
    float rbx = fminf(az, bz), rby = fminf(aw, bw);
    float w = fmaxf(rbx - ltx, 0.f), h = fmaxf(rby - lty, 0.f);
    float inter = w * h;
    float uni = area_a + area_b - inter;
    float iou = inter / (uni + 1e-7f);
    float lcx = fminf(ax, bx), lcy = fminf(ay, by);
    float rcx = fmaxf(az, bz), rcy = fmaxf(aw, bw);
    float wc = fmaxf(rcx - lcx, 0.f), hc = fmaxf(rcy - lcy, 0.f);
    float areac = wc * hc;
    float giou = iou - (areac - uni) / (areac + 1e-7f);
    float gl = 1.f - giou;
    u64 m = __ballot(gl < 0.2f);
    if ((threadIdx.x & 63) == 0)
        cost[((size_t)((b << 9) + i)) * 8 + (j >> 6)] = m;
}

// Exact integer replication of the reference JV Hungarian on a {0,1} cost
// matrix + fused CIoU epilogue.
// R8 structure: with no holes, row i's cursor column is always i-1, and the
// final permutation is IDENTITY except at rare event rows. Wave-parallel
// ballots precompute per-row bits: nz, col0 (=cost[i][0]), diag
// (=cost[i][i-1]), and ap (=(Z_i & Zcache)!=0, recomputed when the col-0
// owner's row changes). Non-interesting rows (nz & !col0 & !diag & !ap, or
// zero rows) provably assign p[i]=i with no state change (after a zero
// fold minv==0 everywhere, the march is a no-op to the cursor, and
// way[cursor]=col0 iff diag). diag-only rows are a 2-write swap. col0/ap
// rows run the full bitset search; delta>0 or a hole falls back to the
// exact general integer JV (zeroing p for free cols first).
__global__ __launch_bounds__(64, 1) void hungarian_kernel(
        const u64* __restrict__ cost,
        const float* __restrict__ prev_boxes,
        const float* __restrict__ curr_boxes,
        const float* __restrict__ image_sizes,
        float* __restrict__ out) {
    int b = blockIdx.x;
    int lane = threadIdx.x;
    __shared__ __align__(16) u64 costL[NQ * 8];   // 32 KB
    __shared__ int p[NQ + 1];
    __shared__ int wayL[NQ + 1];
    __shared__ int u[NQ + 1];
    __shared__ int vv[NQ + 1];
    __shared__ int minvA[NQ + 1];
    __shared__ unsigned char used[NQ + 1];

    {
        const ulonglong2* src = (const ulonglong2*)(cost + (size_t)b * NQ * 8);
        ulonglong2* dst = (ulonglong2*)costL;
        for (int k = lane; k < NQ * 4; k += 64) dst[k] = src[k];
    }
    for (int k = lane; k <= NQ; k += 64) { p[k] = k; wayL[k] = 0; u[k] = 0; vv[k] = 0; }
    __syncthreads();

    // wave-parallel per-row bitsets (bit l of word w = row 64w+l, 0-based)
    u64 nzB[8], c0B[8], dgB[8], apB[8];
#pragma unroll
    for (int w = 0; w < 8; w++) {
        const u64* Zr = costL + (((w << 6) + lane) << 3);
        u64 o = 0ull;
#pragma unroll
        for (int k = 0; k < 8; k++) o |= Zr[k];
        nzB[w] = __ballot(o != 0ull);
        c0B[w] = __ballot((Zr[0] & 1ull) != 0ull);
        dgB[w] = __ballot(((Zr[w] >> lane) & 1ull) != 0ull);
        apB[w] = 0ull;
    }

    // lane-0 serial state (persists across wave-loop iterations)
    bool ownerNZ0 = false;
    int owner0 = 1;
    u64 Zc[8];
#pragma unroll
    for (int k = 0; k < 8; k++) Zc[k] = 0ull;
    int wIdx = 0;
    u64 bits = 0ull, pendMask = ~0ull;
    bool started = false;

    auto intW = [&](int w) -> u64 {
        u64 x = getw8(c0B, w) | getw8(dgB, w);
        if (ownerNZ0) x |= getw8(apB, w);
        return getw8(nzB, w) & x;
    };
    auto runGeneral = [&](int igen) {
        // exact general integer JV for rows igen..NQ (reference semantics).
        // occupied cols are contiguous 1..igen-1; zero p for free cols so
        // the p[j0]==0 free test works (identity was prewritten).
        for (int j = igen; j <= NQ; j++) p[j] = 0;
        for (int i2 = igen; i2 <= NQ; i2++) {
            p[0] = i2;
            for (int j = 0; j <= NQ; j++) { minvA[j] = 0x7fffffff; used[j] = 0; }
            int j0 = 0;
            while (true) {
                used[j0] = 1;
                int i0 = p[j0];
                int ui0 = u[i0];
                const u64* rr = costL + ((size_t)(i0 - 1) << 3);
                int delta = 0x7fffffff, j1 = 0;
                for (int j = 1; j <= NQ; j++) {
                    if (!used[j]) {
                        int cbit = (int)((rr[(j - 1) >> 6] >> ((j - 1) & 63)) & 1ull);
                        int cur = cbit - ui0 - vv[j];
                        if (cur < minvA[j]) { minvA[j] = cur; wayL[j] = (i2 << 10) | j0; }
                        if (minvA[j] < delta) { delta = minvA[j]; j1 = j; }
                    }
                }
                for (int j = 0; j <= NQ; j++) {
                    if (used[j]) { u[p[j]] += delta; vv[j] -= delta; }
                    else minvA[j] -= delta;
                }
                j0 = j1;
                if (p[j0] == 0) break;
            }
            while (j0) {
                int wv = wayL[j0];
                int jn = ((wv >> 10) == i2) ? (wv & 1023) : 0;
                p[j0] = p[jn];
                j0 = jn;
            }
        }
    };

    for (;;) {   // whole-wave loop (uniform control flow at this level)
        int action = 0;   // 1 = recompute apB (Zc changed), 3 = done
        if (lane == 0) {
            if (!started) {
                started = true;
                if (nzB[0] & 1ull) {
                    // row 1 special: col0 is free (cursor=0)
                    u64 Z1[8];
#pragma unroll
                    for (int k = 0; k < 8; k++) Z1[k] = costL[k];
                    if (!(Z1[0] & 1ull)) {
                        // candidate col0 free: p[1]=1 (identity), install cache
                        owner0 = 1; ownerNZ0 = true;
#pragma unroll
                        for (int k = 0; k < 8; k++) Zc[k] = Z1[k];
                        action = 1; pendMask = ~1ull; wIdx = 0;
                    } else {
                        runGeneral(1); action = 3;
                    }
                } else {
                    bits = intW(0) & ~1ull;
                }
            }
            while (action == 0) {
                if (bits == 0ull) {
                    wIdx++;
                    if (wIdx >= 8) { action = 3; break; }
                    bits = intW(wIdx);
                    continue;
                }
                int l = __builtin_ctzll(bits);
                bits &= bits - 1;
                u64 rem = (l == 63) ? 0ull : (~0ull << (l + 1));
                int i = (wIdx << 6) + l + 1;   // 1-based row; cursor col = i-1
                bool c0 = (getw8(c0B, wIdx) >> l) & 1ull;
                bool apb = ownerNZ0 && ((getw8(apB, wIdx) >> l) & 1ull);
                if (!c0 && !apb) {
                    // diag event: relocation (zero owner0) / swap (nz owner0,
                    // ap==0 guarantees Zc[i-1]==0). p[i]=owner0, p[1]=i.
                    p[i] = owner0;
                    p[1] = i;
                    owner0 = i; ownerNZ0 = true;
#pragma unroll
                    for (int k = 0; k < 8; k++) Zc[k] = costL[((i - 1) << 3) + k];
                    action = 1; pendMask = rem;
                } else {
                    // full bitset search (zero duals)
                    int prevO = owner0; bool prevF = ownerNZ0;
                    bool bail = false, hole = false;
                    u64 Z[8];
#pragma unroll
                    for (int k = 0; k < 8; k++) Z[k] = costL[((i - 1) << 3) + k];
                    u64 ones[8], vis[8], nzA[8], nzBf[8];
#pragma unroll
                    for (int k = 0; k < 8; k++) { ones[k] = Z[k]; vis[k] = 0ull; nzA[k] = 0ull; nzBf[k] = 0ull; }
                    int fA_c = 0, fA_p = 0, fB_c = 0, fB_p = 0;
                    int foldn = 0, assignTo = -1;
                    while (true) {
                        int c2 = -1;
#pragma unroll
                        for (int k = 7; k >= 0; k--) {
                            u64 s = ~ones[k] & ~vis[k];
                            if (s != 0ull) c2 = (k << 6) + __builtin_ctzll(s);
                        }
                        if (c2 < 0) { bail = true; break; }       // delta>0 needed
                        if (c2 >= i - 1) {                        // free region
                            if (c2 == i - 1) assignTo = c2;
                            else hole = true;                     // free above cursor
                            break;
                        }
                        int pc = p[c2 + 1];
                        u64 Zo[8];
#pragma unroll
                        for (int k = 0; k < 8; k++) Zo[k] = costL[((pc - 1) << 3) + k];
                        setbit8(vis, c2);
                        u64 nzv[8], ap2 = 0ull;
#pragma unroll
                        for (int k = 0; k < 8; k++) { nzv[k] = ones[k] & ~Zo[k]; ones[k] &= Zo[k]; ap2 |= ones[k]; }
                        if (foldn == 0) {
                            fA_c = c2; fA_p = pc;
#pragma unroll
                            for (int k = 0; k < 8; k++) nzA[k] = nzv[k];
                        } else if (foldn == 1) {
                            fB_c = c2; fB_p = pc;
#pragma unroll
                            for (int k = 0; k < 8; k++) nzBf[k] = nzv[k];
                        } else {
#pragma unroll
                            for (int k = 0; k < 8; k++) {
                                u64 tt = nzv[k];
                                while (tt) { int b2 = __builtin_ctzll(tt); tt &= tt - 1; wayL[(k << 6) + b2 + 1] = (i << 10) | (c2 + 1); }
                            }
                        }
                        foldn++;
                        if (ap2 == 0ull) { assignTo = i - 1; break; }   // shortcut -> cursor
                    }
                    if (bail || hole) {
                        runGeneral(i);
                        action = 3;
                    } else {
                        int cc = assignTo;
                        while (true) {
                            bool inA = getbit8(nzA, cc), inB = getbit8(nzBf, cc);
                            if (inB)      { p[cc + 1] = fB_p; cc = fB_c; }
                            else if (inA) { p[cc + 1] = fA_p; cc = fA_c; }
                            else if (foldn > 2) {
                                int wv = wayL[cc + 1];
                                if ((wv >> 10) == i) { int jn = wv & 1023; p[cc + 1] = p[jn]; cc = jn - 1; }
                                else                 { p[cc + 1] = i; break; }
                            } else { p[cc + 1] = i; break; }
                        }
                        owner0 = p[1];
                        ownerNZ0 = (getw8(nzB, (owner0 - 1) >> 6) >> ((owner0 - 1) & 63)) & 1ull;
                        if (ownerNZ0 && !(prevF && prevO == owner0)) {
#pragma unroll
                            for (int k = 0; k < 8; k++) Zc[k] = costL[((owner0 - 1) << 3) + k];
                            action = 1; pendMask = rem;
                        } else {
                            bits = intW(wIdx) & rem;
                        }
                    }
                }
            }
        }
        action = __shfl(action, 0, 64);
        if (action == 1) {
            // broadcast Zc from lane 0, wave-parallel recompute apB
            u64 zc[8];
#pragma unroll
            for (int k = 0; k < 8; k++) {
                int lo = __shfl((int)(Zc[k] & 0xffffffffull), 0, 64);
                int hi = __shfl((int)(Zc[k] >> 32), 0, 64);
                zc[k] = (((u64)(unsigned)hi) << 32) | (u64)(unsigned)lo;
            }
#pragma unroll
            for (int w = 0; w < 8; w++) {
                const u64* Zr = costL + (((w << 6) + lane) << 3);
                u64 a = 0ull;
#pragma unroll
                for (int k = 0; k < 8; k++) a |= Zr[k] & zc[k];
                apB[w] = __ballot(a != 0ull);
            }
            if (lane == 0) {
                ownerNZ0 = true;
                bits = intW(wIdx) & pendMask;
            }
            continue;
        }
        break;   // action == 3
    }
    __syncthreads();

    // Fused CIoU epilogue: p is a permutation, so summing over columns j
    // (curr idx j-1, filtered idx p[j]-1) == summing over rows.
    {
#pragma clang fp contract(off)
        float H = image_sizes[2 * b + 0];
        float W = image_sizes[2 * b + 1];
        float sum = 0.f;
#pragma unroll
        for (int k = 0; k < 8; k++) {
            int j = 1 + lane + (k << 6);
            int r = p[j] - 1;     // filtered row
            int c = j - 1;        // curr box index
            float4 cb = ((const float4*)curr_boxes)[(b << 9) + c];
            float x1 = cb.x - 0.5f * cb.z, y1 = cb.y - 0.5f * cb.w;
            float x2 = cb.x + 0.5f * cb.z, y2 = cb.y + 0.5f * cb.w;
            float4 pb = ((const float4*)prev_boxes)[(b << 9) + r];
            float fcx = (pb.x * W) / W, fcy = (pb.y * H) / H;
            float fw2 = (pb.z * W) / W, fh2 = (pb.w * H) / H;
            float xg1 = fcx - 0.5f * fw2, yg1 = fcy - 0.5f * fh2;
            float xg2 = fcx + 0.5f * fw2, yg2 = fcy + 0.5f * fh2;
            float iw = fmaxf(fminf(x2, xg2) - fmaxf(x1, xg1), 0.f);
            float ih = fmaxf(fminf(y2, yg2) - fmaxf(y1, yg1), 0.f);
            float inter = iw * ih;
            float uni = (x2 - x1) * (y2 - y1) + (xg2 - xg1) * (yg2 - yg1) - inter;
            float iou = inter / (uni + 1e-7f);
            float cw2 = fmaxf(x2, xg2) - fminf(x1, xg1);
            float ch2 = fmaxf(y2, yg2) - fminf(y1, yg1);
            float c2 = cw2 * cw2 + ch2 * ch2 + 1e-7f;
            float dx = ((x1 + x2) - xg1) - xg2;
            float dy = ((y1 + y2) - yg1) - yg2;
            float d2 = (dx * dx + dy * dy) / 4.f;
            const float CC = (float)(4.0 / (M_PI * M_PI));
            float at = atanf((xg2 - xg1) / (yg2 - yg1)) - atanf((x2 - x1) / (y2 - y1));
            float v = CC * (at * at);
            float alpha = v / (((1.f - iou) + v) + 1e-7f);
            sum += ((1.f - iou) + d2 / c2) + alpha * v;
        }
#pragma unroll
        for (int off = 32; off >= 1; off >>= 1) sum += __shfl_xor(sum, off, 64);
        if (lane == 0) atomicAdd(out, sum * (1.f / 4096.f));
    }
}

extern "C" void kernel_launch(void* const* d_in, const int* in_sizes, int n_in,
                              void* d_out, int out_size, void* d_ws, size_t ws_size,
                              hipStream_t stream) {
    const float* prev_boxes  = (const float*)d_in[0];
    // d_in[1] = prev_logits : dead code (Kalman innovation == 0 exactly)
    const float* curr_boxes  = (const float*)d_in[2];
    const float* image_sizes = (const float*)d_in[3];
    // d_in[4..6] (std weights, log_q_diag) : dead code

    u64* cost = (u64*)d_ws;
    float* out = (float*)d_out;

    cost_kernel<<<(NB * NQ * NQ) / 256, 256, 0, stream>>>(
        prev_boxes, curr_boxes, image_sizes, cost, out);
    hungarian_kernel<<<NB, 64, 0, stream>>>(
        cost, prev_boxes, curr_boxes, image_sizes, out);
}

// Round 9
// 79.491 us; speedup vs baseline: 6.1432x; 1.1512x over previous
//
#include <hip/hip_runtime.h>
#include <stdint.h>
#include <math.h>

#define NB 8
#define NQ 512

typedef unsigned long long u64;

// ---- register-array helpers: constant-index-only access (no scratch spills) ----
static __device__ __forceinline__ u64 getw8(const u64 (&a)[8], int w) {
    u64 r = 0ull;
#pragma unroll
    for (int k = 0; k < 8; k++) if (k == w) r = a[k];
    return r;
}
static __device__ __forceinline__ void setbit8(u64 (&a)[8], int c) {
    int w = c >> 6; u64 m = 1ull << (c & 63);
#pragma unroll
    for (int k = 0; k < 8; k++) if (k == w) a[k] |= m;
}
static __device__ __forceinline__ bool getbit8(const u64 (&a)[8], int c) {
    return (getw8(a, c >> 6) >> (c & 63)) & 1ull;
}

// Fused prep+cost: xyxy conversions inline (bit-identical to reference:
// Kalman innovation == 0 exactly, so filtered = (prev*scale)/scale).
__global__ void cost_kernel(const float* __restrict__ prev_boxes,
                            const float* __restrict__ curr_boxes,
                            const float* __restrict__ image_sizes,
                            u64* __restrict__ cost,
                            float* __restrict__ out) {
#pragma clang fp contract(off)
    int t = blockIdx.x * blockDim.x + threadIdx.x;   // 0 .. NB*NQ*NQ-1
    if (t == 0) out[0] = 0.f;
    int b = t >> 18;
    int rem = t & (NQ * NQ - 1);
    int i = rem >> 9;        // row: curr box
    int j = rem & (NQ - 1);  // col: filtered box
    float4 cb = ((const float4*)curr_boxes)[(b << 9) + i];
    float ax = cb.x - 0.5f * cb.z, ay = cb.y - 0.5f * cb.w;
    float az = cb.x + 0.5f * cb.z, aw = cb.y + 0.5f * cb.w;
    float H = image_sizes[2 * b + 0];
    float W = image_sizes[2 * b + 1];
    float4 pb = ((const float4*)prev_boxes)[(b << 9) + j];
    float fcx = (pb.x * W) / W, fcy = (pb.y * H) / H;
    float fw  = (pb.z * W) / W, fh  = (pb.w * H) / H;
    float bx = fcx - 0.5f * fw, by = fcy - 0.5f * fh;
    float bz = fcx + 0.5f * fw, bw = fcy + 0.5f * fh;
    float area_a = (az - ax) * (aw - ay);
    float area_b = (bz - bx) * (bw - by);
    float ltx = fmaxf(ax, bx), lty = fmaxf(ay, by);
    float rbx = fminf(az, bz), rby = fminf(aw, bw);
    float w = fmaxf(rbx - ltx, 0.f), h = fmaxf(rby - lty, 0.f);
    float inter = w * h;
    float uni = area_a + area_b - inter;
    float iou = inter / (uni + 1e-7f);
    float lcx = fminf(ax, bx), lcy = fminf(ay, by);
    float rcx = fmaxf(az, bz), rcy = fmaxf(aw, bw);
    float wc = fmaxf(rcx - lcx, 0.f), hc = fmaxf(rcy - lcy, 0.f);
    float areac = wc * hc;
    float giou = iou - (areac - uni) / (areac + 1e-7f);
    float gl = 1.f - giou;
    u64 m = __ballot(gl < 0.2f);
    if ((threadIdx.x & 63) == 0)
        cost[((size_t)((b << 9) + i)) * 8 + (j >> 6)] = m;
}

// Exact integer replication of the reference JV Hungarian on a {0,1} cost
// matrix + fused CIoU epilogue. R9: 256-thread block — thread 0 runs the
// R8 serial event walk verbatim; staging, ballot precompute, apB
// recompute, and the CIoU epilogue are 4-wave parallel (R8 lesson: the
// serial walk is ~3 µs; the 64-thread wave-parallel phases dominated).
// Identity-permutation structure: with no holes, row i's cursor column is
// i-1; only rows flagged nz&(col0|diag|ap) need any work. delta>0 or a
// hole falls back to the exact general integer JV.
__global__ __launch_bounds__(256, 1) void hungarian_kernel(
        const u64* __restrict__ cost,
        const float* __restrict__ prev_boxes,
        const float* __restrict__ curr_boxes,
        const float* __restrict__ image_sizes,
        float* __restrict__ out) {
    int b = blockIdx.x;
    int tid = threadIdx.x;
    int lane = tid & 63;
    int wv = tid >> 6;
    __shared__ __align__(16) u64 costL[NQ * 8];   // 32 KB
    __shared__ int p[NQ + 1];
    __shared__ int wayL[NQ + 1];
    __shared__ int u[NQ + 1];
    __shared__ int vv[NQ + 1];
    __shared__ int minvA[NQ + 1];
    __shared__ unsigned char used[NQ + 1];
    __shared__ u64 nzS[8], c0S[8], dgS[8], apS[8], zcS[8];
    __shared__ int actionS;

    {
        const ulonglong2* src = (const ulonglong2*)(cost + (size_t)b * NQ * 8);
        ulonglong2* dst = (ulonglong2*)costL;
        for (int k = tid; k < NQ * 4; k += 256) dst[k] = src[k];
    }
    for (int k = tid; k <= NQ; k += 256) { p[k] = k; wayL[k] = 0; u[k] = 0; vv[k] = 0; }
    __syncthreads();

    // 4-wave ballot precompute: wave wv owns word-groups 2wv, 2wv+1
#pragma unroll
    for (int gi = 0; gi < 2; gi++) {
        int g = 2 * wv + gi;
        const u64* Zr = costL + (((g << 6) + lane) << 3);
        u64 o = 0ull;
#pragma unroll
        for (int k = 0; k < 8; k++) o |= Zr[k];
        u64 nzb = __ballot(o != 0ull);
        u64 c0b = __ballot((Zr[0] & 1ull) != 0ull);
        u64 dgb = __ballot(((Zr[g] >> lane) & 1ull) != 0ull);
        if (lane == 0) { nzS[g] = nzb; c0S[g] = c0b; dgS[g] = dgb; apS[g] = 0ull; }
    }
    __syncthreads();

    // thread-0 serial state (persists across block-loop iterations)
    u64 nzB[8], c0B[8], dgB[8], apB[8];
    bool ownerNZ0 = false;
    int owner0 = 1;
    u64 Zc[8];
    int wIdx = 0;
    u64 bits = 0ull, pendMask = ~0ull;
    bool started = false;
    if (tid == 0) {
#pragma unroll
        for (int k = 0; k < 8; k++) { nzB[k] = nzS[k]; c0B[k] = c0S[k]; dgB[k] = dgS[k]; apB[k] = 0ull; Zc[k] = 0ull; }
    }

    auto intW = [&](int w) -> u64 {
        u64 x = getw8(c0B, w) | getw8(dgB, w);
        if (ownerNZ0) x |= getw8(apB, w);
        return getw8(nzB, w) & x;
    };
    auto runGeneral = [&](int igen) {
        // exact general integer JV for rows igen..NQ (reference semantics).
        // occupied cols are contiguous 1..igen-1; zero p for free cols so
        // the p[j0]==0 free test works (identity was prewritten).
        for (int j = igen; j <= NQ; j++) p[j] = 0;
        for (int i2 = igen; i2 <= NQ; i2++) {
            p[0] = i2;
            for (int j = 0; j <= NQ; j++) { minvA[j] = 0x7fffffff; used[j] = 0; }
            int j0 = 0;
            while (true) {
                used[j0] = 1;
                int i0 = p[j0];
                int ui0 = u[i0];
                const u64* rr = costL + ((size_t)(i0 - 1) << 3);
                int delta = 0x7fffffff, j1 = 0;
                for (int j = 1; j <= NQ; j++) {
                    if (!used[j]) {
                        int cbit = (int)((rr[(j - 1) >> 6] >> ((j - 1) & 63)) & 1ull);
                        int cur = cbit - ui0 - vv[j];
                        if (cur < minvA[j]) { minvA[j] = cur; wayL[j] = (i2 << 10) | j0; }
                        if (minvA[j] < delta) { delta = minvA[j]; j1 = j; }
                    }
                }
                for (int j = 0; j <= NQ; j++) {
                    if (used[j]) { u[p[j]] += delta; vv[j] -= delta; }
                    else minvA[j] -= delta;
                }
                j0 = j1;
                if (p[j0] == 0) break;
            }
            while (j0) {
                int wv2 = wayL[j0];
                int jn = ((wv2 >> 10) == i2) ? (wv2 & 1023) : 0;
                p[j0] = p[jn];
                j0 = jn;
            }
        }
    };

    for (;;) {   // block-uniform loop
        if (tid == 0) {
            int action = 0;   // 1 = recompute apB (Zc changed), 3 = done
            if (!started) {
                started = true;
                if (nzB[0] & 1ull) {
                    // row 1 special: col0 is free (cursor=0)
                    u64 Z1[8];
#pragma unroll
                    for (int k = 0; k < 8; k++) Z1[k] = costL[k];
                    if (!(Z1[0] & 1ull)) {
                        owner0 = 1; ownerNZ0 = true;
#pragma unroll
                        for (int k = 0; k < 8; k++) Zc[k] = Z1[k];
                        action = 1; pendMask = ~1ull; wIdx = 0;
                    } else {
                        runGeneral(1); action = 3;
                    }
                } else {
                    bits = intW(0) & ~1ull;
                }
            }
            while (action == 0) {
                if (bits == 0ull) {
                    wIdx++;
                    if (wIdx >= 8) { action = 3; break; }
                    bits = intW(wIdx);
                    continue;
                }
                int l = __builtin_ctzll(bits);
                bits &= bits - 1;
                u64 rem = (l == 63) ? 0ull : (~0ull << (l + 1));
                int i = (wIdx << 6) + l + 1;   // 1-based row; cursor col = i-1
                bool c0 = (getw8(c0B, wIdx) >> l) & 1ull;
                bool apb = ownerNZ0 && ((getw8(apB, wIdx) >> l) & 1ull);
                if (!c0 && !apb) {
                    // diag event: relocation (zero owner0) / swap (nz owner0,
                    // ap==0 guarantees Zc[i-1]==0). p[i]=owner0, p[1]=i.
                    p[i] = owner0;
                    p[1] = i;
                    owner0 = i; ownerNZ0 = true;
#pragma unroll
                    for (int k = 0; k < 8; k++) Zc[k] = costL[((i - 1) << 3) + k];
                    action = 1; pendMask = rem;
                } else {
                    // full bitset search (zero duals)
                    int prevO = owner0; bool prevF = ownerNZ0;
                    bool bail = false, hole = false;
                    u64 Z[8];
#pragma unroll
                    for (int k = 0; k < 8; k++) Z[k] = costL[((i - 1) << 3) + k];
                    u64 ones[8], vis[8], nzA[8], nzBf[8];
#pragma unroll
                    for (int k = 0; k < 8; k++) { ones[k] = Z[k]; vis[k] = 0ull; nzA[k] = 0ull; nzBf[k] = 0ull; }
                    int fA_c = 0, fA_p = 0, fB_c = 0, fB_p = 0;
                    int foldn = 0, assignTo = -1;
                    while (true) {
                        int c2 = -1;
#pragma unroll
                        for (int k = 7; k >= 0; k--) {
                            u64 s = ~ones[k] & ~vis[k];
                            if (s != 0ull) c2 = (k << 6) + __builtin_ctzll(s);
                        }
                        if (c2 < 0) { bail = true; break; }       // delta>0 needed
                        if (c2 >= i - 1) {                        // free region
                            if (c2 == i - 1) assignTo = c2;
                            else hole = true;                     // free above cursor
                            break;
                        }
                        int pc = p[c2 + 1];
                        u64 Zo[8];
#pragma unroll
                        for (int k = 0; k < 8; k++) Zo[k] = costL[((pc - 1) << 3) + k];
                        setbit8(vis, c2);
                        u64 nzv[8], ap2 = 0ull;
#pragma unroll
                        for (int k = 0; k < 8; k++) { nzv[k] = ones[k] & ~Zo[k]; ones[k] &= Zo[k]; ap2 |= ones[k]; }
                        if (foldn == 0) {
                            fA_c = c2; fA_p = pc;
#pragma unroll
                            for (int k = 0; k < 8; k++) nzA[k] = nzv[k];
                        } else if (foldn == 1) {
                            fB_c = c2; fB_p = pc;
#pragma unroll
                            for (int k = 0; k < 8; k++) nzBf[k] = nzv[k];
                        } else {
#pragma unroll
                            for (int k = 0; k < 8; k++) {
                                u64 tt = nzv[k];
                                while (tt) { int b2 = __builtin_ctzll(tt); tt &= tt - 1; wayL[(k << 6) + b2 + 1] = (i << 10) | (c2 + 1); }
                            }
                        }
                        foldn++;
                        if (ap2 == 0ull) { assignTo = i - 1; break; }   // shortcut -> cursor
                    }
                    if (bail || hole) {
                        runGeneral(i);
                        action = 3;
                    } else {
                        int cc = assignTo;
                        while (true) {
                            bool inA = getbit8(nzA, cc), inB = getbit8(nzBf, cc);
                            if (inB)      { p[cc + 1] = fB_p; cc = fB_c; }
                            else if (inA) { p[cc + 1] = fA_p; cc = fA_c; }
                            else if (foldn > 2) {
                                int wv2 = wayL[cc + 1];
                                if ((wv2 >> 10) == i) { int jn = wv2 & 1023; p[cc + 1] = p[jn]; cc = jn - 1; }
                                else                  { p[cc + 1] = i; break; }
                            } else { p[cc + 1] = i; break; }
                        }
                        owner0 = p[1];
                        ownerNZ0 = (getw8(nzB, (owner0 - 1) >> 6) >> ((owner0 - 1) & 63)) & 1ull;
                        if (ownerNZ0 && !(prevF && prevO == owner0)) {
#pragma unroll
                            for (int k = 0; k < 8; k++) Zc[k] = costL[((owner0 - 1) << 3) + k];
                            action = 1; pendMask = rem;
                        } else {
                            bits = intW(wIdx) & rem;
                        }
                    }
                }
            }
            if (action == 1) {
#pragma unroll
                for (int k = 0; k < 8; k++) zcS[k] = Zc[k];
            }
            actionS = action;
        }
        __syncthreads();
        int action = actionS;
        if (action == 1) {
            // 4-wave recompute of apB: wave wv owns word-groups 2wv, 2wv+1
            u64 zc[8];
#pragma unroll
            for (int k = 0; k < 8; k++) zc[k] = zcS[k];
#pragma unroll
            for (int gi = 0; gi < 2; gi++) {
                int g = 2 * wv + gi;
                const u64* Zr = costL + (((g << 6) + lane) << 3);
                u64 a = 0ull;
#pragma unroll
                for (int k = 0; k < 8; k++) a |= Zr[k] & zc[k];
                u64 bal = __ballot(a != 0ull);
                if (lane == 0) apS[g] = bal;
            }
            __syncthreads();
            if (tid == 0) {
#pragma unroll
                for (int k = 0; k < 8; k++) apB[k] = apS[k];
                ownerNZ0 = true;
                bits = intW(wIdx) & pendMask;
            }
            continue;
        }
        break;   // action == 3
    }
    __syncthreads();

    // Fused CIoU epilogue: p is a permutation, so summing over columns j
    // (curr idx j-1, filtered idx p[j]-1) == summing over rows.
    {
#pragma clang fp contract(off)
        float H = image_sizes[2 * b + 0];
        float W = image_sizes[2 * b + 1];
        float sum = 0.f;
#pragma unroll
        for (int k = 0; k < 2; k++) {
            int j = 1 + tid + (k << 8);
            int r = p[j] - 1;     // filtered row
            int c = j - 1;        // curr box index
            float4 cb = ((const float4*)curr_boxes)[(b << 9) + c];
            float x1 = cb.x - 0.5f * cb.z, y1 = cb.y - 0.5f * cb.w;
            float x2 = cb.x + 0.5f * cb.z, y2 = cb.y + 0.5f * cb.w;
            float4 pb = ((const float4*)prev_boxes)[(b << 9) + r];
            float fcx = (pb.x * W) / W, fcy = (pb.y * H) / H;
            float fw2 = (pb.z * W) / W, fh2 = (pb.w * H) / H;
            float xg1 = fcx - 0.5f * fw2, yg1 = fcy - 0.5f * fh2;
            float xg2 = fcx + 0.5f * fw2, yg2 = fcy + 0.5f * fh2;
            float iw = fmaxf(fminf(x2, xg2) - fmaxf(x1, xg1), 0.f);
            float ih = fmaxf(fminf(y2, yg2) - fmaxf(y1, yg1), 0.f);
            float inter = iw * ih;
            float uni = (x2 - x1) * (y2 - y1) + (xg2 - xg1) * (yg2 - yg1) - inter;
            float iou = inter / (uni + 1e-7f);
            float cw2 = fmaxf(x2, xg2) - fminf(x1, xg1);
            float ch2 = fmaxf(y2, yg2) - fminf(y1, yg1);
            float c2 = cw2 * cw2 + ch2 * ch2 + 1e-7f;
            float dx = ((x1 + x2) - xg1) - xg2;
            float dy = ((y1 + y2) - yg1) - yg2;
            float d2 = (dx * dx + dy * dy) / 4.f;
            const float CC = (float)(4.0 / (M_PI * M_PI));
            float at = atanf((xg2 - xg1) / (yg2 - yg1)) - atanf((x2 - x1) / (y2 - y1));
            float v = CC * (at * at);
            float alpha = v / (((1.f - iou) + v) + 1e-7f);
            sum += ((1.f - iou) + d2 / c2) + alpha * v;
        }
#pragma unroll
        for (int off = 32; off >= 1; off >>= 1) sum += __shfl_xor(sum, off, 64);
        if (lane == 0) atomicAdd(out, sum * (1.f / 4096.f));
    }
}

extern "C" void kernel_launch(void* const* d_in, const int* in_sizes, int n_in,
                              void* d_out, int out_size, void* d_ws, size_t ws_size,
                              hipStream_t stream) {
    const float* prev_boxes  = (const float*)d_in[0];
    // d_in[1] = prev_logits : dead code (Kalman innovation == 0 exactly)
    const float* curr_boxes  = (const float*)d_in[2];
    const float* image_sizes = (const float*)d_in[3];
    // d_in[4..6] (std weights, log_q_diag) : dead code

    u64* cost = (u64*)d_ws;
    float* out = (float*)d_out;

    cost_kernel<<<(NB * NQ * NQ) / 256, 256, 0, stream>>>(
        prev_boxes, curr_boxes, image_sizes, cost, out);
    hungarian_kernel<<<NB, 256, 0, stream>>>(
        cost, prev_boxes, curr_boxes, image_sizes, out);
}